// Round 1
// baseline (353.562 us; speedup 1.0000x reference)
//
#include <hip/hip_runtime.h>

#define DM 1024
#define NH 16
#define DK 64
#define SEQ 2048

typedef __attribute__((ext_vector_type(8))) __bf16 bf16x8;
typedef __attribute__((ext_vector_type(4))) float f32x4;
typedef __attribute__((ext_vector_type(8))) unsigned short u16x8;
typedef unsigned short u16;

#define MFMA(a, b, c) __builtin_amdgcn_mfma_f32_16x16x32_bf16(a, b, c, 0, 0, 0)

__device__ __forceinline__ u16 f2bf(float f) {
    unsigned u = __builtin_bit_cast(unsigned, f);
    u = (u + 0x7FFFu + ((u >> 16) & 1u)) >> 16;
    return (u16)u;
}

__device__ __forceinline__ bf16x8 ldb(const u16* p) {
    u16x8 v = *(const u16x8*)p;
    return __builtin_bit_cast(bf16x8, v);
}

// ---------------- elementwise f32 -> bf16 (vectorized x4) ----------------
__global__ __launch_bounds__(256) void k_cvt_bf16(const float* __restrict__ in,
                                                  u16* __restrict__ out, int n4) {
    int i = blockIdx.x * 256 + threadIdx.x;
    if (i < n4) {
        float4 v = ((const float4*)in)[i];
        ushort4 o;
        o.x = f2bf(v.x); o.y = f2bf(v.y); o.z = f2bf(v.z); o.w = f2bf(v.w);
        ((ushort4*)out)[i] = o;
    }
}

// ---------------- tiled transpose + convert: W[K][N] f32 -> WT[N][K] bf16 ----------------
__global__ __launch_bounds__(256) void k_transpose(const float* __restrict__ W,
                                                   u16* __restrict__ WT, int K, int N) {
    __shared__ float t[32][33];
    int n0 = blockIdx.x * 32, k0 = blockIdx.y * 32;
    int tx = threadIdx.x & 31, ty = threadIdx.x >> 5;
#pragma unroll
    for (int i = 0; i < 32; i += 8)
        t[ty + i][tx] = W[(long)(k0 + ty + i) * N + n0 + tx];
    __syncthreads();
#pragma unroll
    for (int i = 0; i < 32; i += 8)
        WT[(long)(n0 + ty + i) * K + k0 + tx] = f2bf(t[tx][ty + i]);
}

// ---------------- bf16 GEMM: C[M][N] f32 = A[M][K] * BT[N][K]^T ----------------
// 64x64 tile, BK=64, 4 waves (each 32x32), mfma_f32_16x16x32_bf16
__global__ __launch_bounds__(256) void k_gemm(const u16* __restrict__ A,
                                              const u16* __restrict__ BT,
                                              float* __restrict__ C, int N, int K) {
    __shared__ __align__(16) u16 As[64][72];
    __shared__ __align__(16) u16 Bs[64][72];
    int tid = threadIdx.x;
    int w = tid >> 6, lane = tid & 63, lg = lane >> 4, lr = lane & 15;
    int wr = w >> 1, wc = w & 1;
    int m0 = blockIdx.y * 64, n0 = blockIdx.x * 64;
    f32x4 acc[2][2] = {};
    for (int k0 = 0; k0 < K; k0 += 64) {
#pragma unroll
        for (int i = 0; i < 2; ++i) {
            int q = tid + i * 256;
            int row = q >> 3, ch = (q & 7) * 8;
            *(u16x8*)&As[row][ch] = *(const u16x8*)(A + (long)(m0 + row) * K + k0 + ch);
            *(u16x8*)&Bs[row][ch] = *(const u16x8*)(BT + (long)(n0 + row) * K + k0 + ch);
        }
        __syncthreads();
#pragma unroll
        for (int kk = 0; kk < 64; kk += 32) {
            bf16x8 a0 = ldb(&As[wr * 32 + lr][kk + lg * 8]);
            bf16x8 a1 = ldb(&As[wr * 32 + 16 + lr][kk + lg * 8]);
            bf16x8 b0 = ldb(&Bs[wc * 32 + lr][kk + lg * 8]);
            bf16x8 b1 = ldb(&Bs[wc * 32 + 16 + lr][kk + lg * 8]);
            acc[0][0] = MFMA(a0, b0, acc[0][0]);
            acc[0][1] = MFMA(a0, b1, acc[0][1]);
            acc[1][0] = MFMA(a1, b0, acc[1][0]);
            acc[1][1] = MFMA(a1, b1, acc[1][1]);
        }
        __syncthreads();
    }
#pragma unroll
    for (int mi = 0; mi < 2; ++mi)
#pragma unroll
        for (int ni = 0; ni < 2; ++ni)
#pragma unroll
            for (int r = 0; r < 4; ++r) {
                int row = m0 + wr * 32 + mi * 16 + lg * 4 + r;
                int col = n0 + wc * 32 + ni * 16 + lr;
                C[(long)row * N + col] = acc[mi][ni][r];
            }
}

// ---------------- RoPE for Q: read f32, write bf16 in-place layout ----------------
__global__ __launch_bounds__(256) void k_rope_q(const float* __restrict__ Qf,
                                                u16* __restrict__ Qb) {
    int idx = blockIdx.x * 256 + threadIdx.x;  // B*S*NH*32
    int i = idx & 31;
    int h = (idx >> 5) & 15;
    int r = idx >> 9;  // b*S + s
    int s = r & (SEQ - 1);
    float theta = exp2f(-(float)i * 0.4152410118609203f);  // 10000^(-2i/64)
    float ang = (float)s * theta;
    float sn, cs;
    sincosf(ang, &sn, &cs);
    const float* p = Qf + (long)r * DM + h * DK + 2 * i;
    float x1 = p[0], x2 = p[1];
    u16* o = Qb + (long)r * DM + h * DK + 2 * i;
    o[0] = f2bf(x1 * cs - x2 * sn);
    o[1] = f2bf(x2 * cs + x1 * sn);
}

// ---------------- RoPE for K ----------------
__global__ __launch_bounds__(256) void k_rope_k(const float* __restrict__ Kf,
                                                u16* __restrict__ Kb) {
    int idx = blockIdx.x * 256 + threadIdx.x;  // B*S*32
    int i = idx & 31;
    int r = idx >> 5;  // b*S + s
    int s = r & (SEQ - 1);
    float theta = exp2f(-(float)i * 0.4152410118609203f);
    float ang = (float)s * theta;
    float sn, cs;
    sincosf(ang, &sn, &cs);
    const float* p = Kf + (long)r * DK + 2 * i;
    float x1 = p[0], x2 = p[1];
    u16* o = Kb + (long)r * DK + 2 * i;
    o[0] = f2bf(x1 * cs - x2 * sn);
    o[1] = f2bf(x2 * cs + x1 * sn);
}

// ---------------- flash attention, causal, MQA ----------------
// grid: (S/64, NH, B), 256 threads = 4 independent waves, 16 q-rows each.
// S^T = mfma(K, Q) so each lane owns one q column; P restaged via LDS for PV.
__global__ __launch_bounds__(256) void k_attn(const u16* __restrict__ Qb,
                                              const u16* __restrict__ Kb,
                                              const u16* __restrict__ VbT,
                                              u16* __restrict__ Ob) {
    __shared__ __align__(16) u16 Plds[4][16][72];
    int b = blockIdx.z, h = blockIdx.y;
    int w = threadIdx.x >> 6, lane = threadIdx.x & 63;
    int lg = lane >> 4, lr = lane & 15;
    int q0 = blockIdx.x * 64 + w * 16;
    const u16* Qp = Qb + (long)(b * SEQ + q0 + lr) * DM + h * DK;
    bf16x8 qf0 = ldb(Qp + lg * 8);
    bf16x8 qf1 = ldb(Qp + 32 + lg * 8);
    f32x4 oacc[4] = {};
    float m = -1e30f, lsum = 0.f;
    int q = q0 + lr;
    const u16* Kbase = Kb + (long)b * SEQ * DK;
    const u16* Vbase = VbT + (long)b * DK * SEQ;
    for (int kv0 = 0; kv0 <= q0 + 15; kv0 += 64) {
        f32x4 sacc[4];
#pragma unroll
        for (int sub = 0; sub < 4; ++sub) {
            const u16* Kp = Kbase + (long)(kv0 + sub * 16 + lr) * DK;
            f32x4 z = {0.f, 0.f, 0.f, 0.f};
            z = MFMA(ldb(Kp + lg * 8), qf0, z);
            z = MFMA(ldb(Kp + 32 + lg * 8), qf1, z);
            sacc[sub] = z;
        }
        float tmax = -1e30f;
#pragma unroll
        for (int sub = 0; sub < 4; ++sub)
#pragma unroll
            for (int r = 0; r < 4; ++r) {
                int kv = kv0 + sub * 16 + lg * 4 + r;
                float v = sacc[sub][r] * 0.125f;
                if (kv > q) v = -1e30f;
                sacc[sub][r] = v;
                tmax = fmaxf(tmax, v);
            }
        tmax = fmaxf(tmax, __shfl_xor(tmax, 16));
        tmax = fmaxf(tmax, __shfl_xor(tmax, 32));
        float mnew = fmaxf(m, tmax);
        float fac = expf(m - mnew);
        float psum = 0.f;
#pragma unroll
        for (int sub = 0; sub < 4; ++sub)
#pragma unroll
            for (int r = 0; r < 4; ++r) {
                float p = expf(sacc[sub][r] - mnew);
                psum += p;
                Plds[w][lr][sub * 16 + lg * 4 + r] = f2bf(p);
            }
        psum += __shfl_xor(psum, 16);
        psum += __shfl_xor(psum, 32);
        lsum = lsum * fac + psum;
        m = mnew;
        float fr[4];
#pragma unroll
        for (int r = 0; r < 4; ++r) fr[r] = __shfl(fac, lg * 4 + r);
#pragma unroll
        for (int dt = 0; dt < 4; ++dt)
#pragma unroll
            for (int r = 0; r < 4; ++r) oacc[dt][r] *= fr[r];
#pragma unroll
        for (int kk = 0; kk < 2; ++kk) {
            bf16x8 pf = ldb(&Plds[w][lr][kk * 32 + lg * 8]);
#pragma unroll
            for (int dt = 0; dt < 4; ++dt) {
                bf16x8 vf = ldb(Vbase + (long)(dt * 16 + lr) * SEQ + kv0 + kk * 32 + lg * 8);
                oacc[dt] = MFMA(pf, vf, oacc[dt]);
            }
        }
    }
    float li[4];
#pragma unroll
    for (int r = 0; r < 4; ++r) li[r] = 1.f / __shfl(lsum, lg * 4 + r);
    u16* Op = Ob + (long)(b * SEQ + q0) * DM + h * DK;
#pragma unroll
    for (int dt = 0; dt < 4; ++dt)
#pragma unroll
        for (int r = 0; r < 4; ++r)
            Op[(long)(lg * 4 + r) * DM + dt * 16 + lr] = f2bf(oacc[dt][r] * li[r]);
}

extern "C" void kernel_launch(void* const* d_in, const int* in_sizes, int n_in,
                              void* d_out, int out_size, void* d_ws, size_t ws_size,
                              hipStream_t stream) {
    const float* x = (const float*)d_in[0];
    const float* Wq = (const float*)d_in[1];
    const float* Wk = (const float*)d_in[2];
    const float* Wv = (const float*)d_in[3];
    const float* Wo = (const float*)d_in[4];
    float* out = (float*)d_out;

    const int M = 2 * SEQ;  // 4096 rows
    char* p = (char*)d_ws;
    u16* xb = (u16*)p;      p += (size_t)M * DM * 2;          // 8 MB
    u16* WqbT = (u16*)p;    p += (size_t)DM * DM * 2;         // 2 MB
    u16* WkbT = (u16*)p;    p += (size_t)DK * DM * 2;         // 128 KB
    u16* WvbT = (u16*)p;    p += (size_t)DK * DM * 2;         // 128 KB
    u16* WobT = (u16*)p;    p += (size_t)DM * DM * 2;         // 2 MB
    float* Kf = (float*)p;  p += (size_t)M * DK * 4;          // 1 MB
    float* Vf = (float*)p;  p += (size_t)M * DK * 4;          // 1 MB
    u16* Qb = (u16*)p;      p += (size_t)M * DM * 2;          // 8 MB
    u16* Kb = (u16*)p;      p += (size_t)M * DK * 2;          // 512 KB
    u16* VbT = (u16*)p;     p += (size_t)M * DK * 2;          // 512 KB
    u16* Ob = (u16*)p;      p += (size_t)M * DM * 2;          // 8 MB
    float* Qf = out;  // reuse d_out (16 MB fp32) as scratch for pre-RoPE Q

    // 1) convert inputs to bf16 (+ weight transposes)
    k_cvt_bf16<<<(M * DM / 4 + 255) / 256, 256, 0, stream>>>(x, xb, M * DM / 4);
    k_transpose<<<dim3(DM / 32, DM / 32), 256, 0, stream>>>(Wq, WqbT, DM, DM);
    k_transpose<<<dim3(DK / 32, DM / 32), 256, 0, stream>>>(Wk, WkbT, DM, DK);
    k_transpose<<<dim3(DK / 32, DM / 32), 256, 0, stream>>>(Wv, WvbT, DM, DK);
    k_transpose<<<dim3(DM / 32, DM / 32), 256, 0, stream>>>(Wo, WobT, DM, DM);

    // 2) projections
    k_gemm<<<dim3(DM / 64, M / 64), 256, 0, stream>>>(xb, WqbT, Qf, DM, DM);
    k_gemm<<<dim3(1, M / 64), 256, 0, stream>>>(xb, WkbT, Kf, DK, DM);
    k_gemm<<<dim3(1, M / 64), 256, 0, stream>>>(xb, WvbT, Vf, DK, DM);

    // 3) RoPE + V transpose (to bf16)
    k_rope_q<<<(M * NH * 32) / 256, 256, 0, stream>>>(Qf, Qb);
    k_rope_k<<<(M * 32) / 256, 256, 0, stream>>>(Kf, Kb);
    for (int bb = 0; bb < 2; ++bb)
        k_transpose<<<dim3(DK / 32, SEQ / 32), 256, 0, stream>>>(
            Vf + (long)bb * SEQ * DK, VbT + (long)bb * DK * SEQ, SEQ, DK);
    // NOTE: k_transpose writes bf16 WT[N][K]; here W=V[S][DK] -> VbT[DK][S] per batch.

    // 4) attention
    k_attn<<<dim3(SEQ / 64, NH, 2), 256, 0, stream>>>(Qb, Kb, VbT, Ob);

    // 5) output projection -> d_out (overwrites Qf scratch)
    k_gemm<<<dim3(DM / 64, M / 64), 256, 0, stream>>>(Ob, WobT, out, DM, DM);
}

// Round 2
// 334.095 us; speedup vs baseline: 1.0583x; 1.0583x over previous
//
#include <hip/hip_runtime.h>

#define DM 1024
#define NH 16
#define DK 64
#define SEQ 2048

typedef __attribute__((ext_vector_type(8))) __bf16 bf16x8;
typedef __attribute__((ext_vector_type(4))) float f32x4;
typedef __attribute__((ext_vector_type(8))) unsigned short u16x8;
typedef unsigned short u16;

#define MFMA(a, b, c) __builtin_amdgcn_mfma_f32_16x16x32_bf16(a, b, c, 0, 0, 0)

__device__ __forceinline__ u16 f2bf(float f) {
    unsigned u = __builtin_bit_cast(unsigned, f);
    u = (u + 0x7FFFu + ((u >> 16) & 1u)) >> 16;
    return (u16)u;
}

__device__ __forceinline__ bf16x8 ldb(const u16* p) {
    u16x8 v = *(const u16x8*)p;
    return __builtin_bit_cast(bf16x8, v);
}

// ---------------- elementwise f32 -> bf16 (vectorized x4) ----------------
__global__ __launch_bounds__(256) void k_cvt_bf16(const float* __restrict__ in,
                                                  u16* __restrict__ out, int n4) {
    int i = blockIdx.x * 256 + threadIdx.x;
    if (i < n4) {
        float4 v = ((const float4*)in)[i];
        ushort4 o;
        o.x = f2bf(v.x); o.y = f2bf(v.y); o.z = f2bf(v.z); o.w = f2bf(v.w);
        ((ushort4*)out)[i] = o;
    }
}

// ------ tiled transpose + convert: W[K][ldW] (cols n0..) f32 -> WT[N][K] bf16 ------
__global__ __launch_bounds__(256) void k_transpose(const float* __restrict__ W,
                                                   u16* __restrict__ WT, int ldW,
                                                   int K, int N) {
    __shared__ float t[32][33];
    int n0 = blockIdx.x * 32, k0 = blockIdx.y * 32;
    int tx = threadIdx.x & 31, ty = threadIdx.x >> 5;
#pragma unroll
    for (int i = 0; i < 32; i += 8)
        t[ty + i][tx] = W[(long)(k0 + ty + i) * ldW + n0 + tx];
    __syncthreads();
#pragma unroll
    for (int i = 0; i < 32; i += 8)
        WT[(long)(n0 + ty + i) * K + k0 + tx] = f2bf(t[tx][ty + i]);
}

// ---------------- bf16 GEMM: C[M][N] f32 = A[M][K] * BT[N][K]^T ----------------
__global__ __launch_bounds__(256) void k_gemm(const u16* __restrict__ A,
                                              const u16* __restrict__ BT,
                                              float* __restrict__ C, int N, int K) {
    __shared__ __align__(16) u16 As[64][72];
    __shared__ __align__(16) u16 Bs[64][72];
    int tid = threadIdx.x;
    int w = tid >> 6, lane = tid & 63, lg = lane >> 4, lr = lane & 15;
    int wr = w >> 1, wc = w & 1;
    int m0 = blockIdx.y * 64, n0 = blockIdx.x * 64;
    f32x4 acc[2][2] = {};
    for (int k0 = 0; k0 < K; k0 += 64) {
#pragma unroll
        for (int i = 0; i < 2; ++i) {
            int q = tid + i * 256;
            int row = q >> 3, ch = (q & 7) * 8;
            *(u16x8*)&As[row][ch] = *(const u16x8*)(A + (long)(m0 + row) * K + k0 + ch);
            *(u16x8*)&Bs[row][ch] = *(const u16x8*)(BT + (long)(n0 + row) * K + k0 + ch);
        }
        __syncthreads();
#pragma unroll
        for (int kk = 0; kk < 64; kk += 32) {
            bf16x8 a0 = ldb(&As[wr * 32 + lr][kk + lg * 8]);
            bf16x8 a1 = ldb(&As[wr * 32 + 16 + lr][kk + lg * 8]);
            bf16x8 b0 = ldb(&Bs[wc * 32 + lr][kk + lg * 8]);
            bf16x8 b1 = ldb(&Bs[wc * 32 + 16 + lr][kk + lg * 8]);
            acc[0][0] = MFMA(a0, b0, acc[0][0]);
            acc[0][1] = MFMA(a0, b1, acc[0][1]);
            acc[1][0] = MFMA(a1, b0, acc[1][0]);
            acc[1][1] = MFMA(a1, b1, acc[1][1]);
        }
        __syncthreads();
    }
#pragma unroll
    for (int mi = 0; mi < 2; ++mi)
#pragma unroll
        for (int ni = 0; ni < 2; ++ni)
#pragma unroll
            for (int r = 0; r < 4; ++r) {
                int row = m0 + wr * 32 + mi * 16 + lg * 4 + r;
                int col = n0 + wc * 32 + ni * 16 + lr;
                C[(long)row * N + col] = acc[mi][ni][r];
            }
}

// ---------------- RoPE for Q: read f32, write bf16 ----------------
__global__ __launch_bounds__(256) void k_rope_q(const float* __restrict__ Qf,
                                                u16* __restrict__ Qb) {
    int idx = blockIdx.x * 256 + threadIdx.x;  // B*S*NH*32
    int i = idx & 31;
    int h = (idx >> 5) & 15;
    int r = idx >> 9;  // b*S + s
    int s = r & (SEQ - 1);
    float theta = exp2f(-(float)i * 0.4152410118609203f);  // 10000^(-2i/64)
    float ang = (float)s * theta;
    float sn, cs;
    sincosf(ang, &sn, &cs);
    const float* p = Qf + (long)r * DM + h * DK + 2 * i;
    float x1 = p[0], x2 = p[1];
    u16* o = Qb + (long)r * DM + h * DK + 2 * i;
    o[0] = f2bf(x1 * cs - x2 * sn);
    o[1] = f2bf(x2 * cs + x1 * sn);
}

// ---------------- RoPE for K (reads fused KV buffer, row stride 128) ----------------
__global__ __launch_bounds__(256) void k_rope_k(const float* __restrict__ KVf,
                                                u16* __restrict__ Kb) {
    int idx = blockIdx.x * 256 + threadIdx.x;  // B*S*32
    int i = idx & 31;
    int r = idx >> 5;  // b*S + s
    int s = r & (SEQ - 1);
    float theta = exp2f(-(float)i * 0.4152410118609203f);
    float ang = (float)s * theta;
    float sn, cs;
    sincosf(ang, &sn, &cs);
    const float* p = KVf + (long)r * 128 + 2 * i;
    float x1 = p[0], x2 = p[1];
    u16* o = Kb + (long)r * DK + 2 * i;
    o[0] = f2bf(x1 * cs - x2 * sn);
    o[1] = f2bf(x2 * cs + x1 * sn);
}

// ---------------- flash attention, causal, MQA ----------------
// grid: (S/64, NH, B), 4 independent waves, 16 q-rows each, KV tile = 128.
// Blocks mapped in reverse so longest causal loops launch first.
__global__ __launch_bounds__(256) void k_attn(const u16* __restrict__ Qb,
                                              const u16* __restrict__ Kb,
                                              const u16* __restrict__ VbT,
                                              u16* __restrict__ Ob) {
    __shared__ __align__(16) u16 Plds[4][16][136];
    int b = blockIdx.z, h = blockIdx.y;
    int w = threadIdx.x >> 6, lane = threadIdx.x & 63;
    int lg = lane >> 4, lr = lane & 15;
    int q0 = (gridDim.x - 1 - blockIdx.x) * 64 + w * 16;
    int qmax = q0 + 15;
    int q = q0 + lr;
    const u16* Qp = Qb + (long)(b * SEQ + q0 + lr) * DM + h * DK;
    bf16x8 qf0 = ldb(Qp + lg * 8);
    bf16x8 qf1 = ldb(Qp + 32 + lg * 8);
    f32x4 oacc[4] = {};
    float m = -1e30f, lsum = 0.f;
    const u16* Kbase = Kb + (long)b * SEQ * DK;
    const u16* Vbase = VbT + (long)b * DK * SEQ;
    const float SC = 0.18033688011112042f;  // 0.125 * log2(e)

    for (int kv0 = 0; kv0 <= qmax; kv0 += 128) {
        f32x4 sacc[8];
#pragma unroll
        for (int sub = 0; sub < 8; ++sub) {
            f32x4 z = {0.f, 0.f, 0.f, 0.f};
            if (kv0 + sub * 16 <= qmax) {
                const u16* Kp = Kbase + (long)(kv0 + sub * 16 + lr) * DK;
                z = MFMA(ldb(Kp + lg * 8), qf0, z);
                z = MFMA(ldb(Kp + 32 + lg * 8), qf1, z);
            }
            sacc[sub] = z;
        }
        float tmax = -1e30f;
#pragma unroll
        for (int sub = 0; sub < 8; ++sub)
#pragma unroll
            for (int r = 0; r < 4; ++r) {
                int kv = kv0 + sub * 16 + lg * 4 + r;
                float v = sacc[sub][r] * SC;
                if (kv > q) v = -1e30f;
                sacc[sub][r] = v;
                tmax = fmaxf(tmax, v);
            }
        tmax = fmaxf(tmax, __shfl_xor(tmax, 16));
        tmax = fmaxf(tmax, __shfl_xor(tmax, 32));
        float mnew = fmaxf(m, tmax);
        float fac = exp2f(m - mnew);
        float psum = 0.f;
#pragma unroll
        for (int sub = 0; sub < 8; ++sub) {
            float p0 = exp2f(sacc[sub][0] - mnew);
            float p1 = exp2f(sacc[sub][1] - mnew);
            float p2 = exp2f(sacc[sub][2] - mnew);
            float p3 = exp2f(sacc[sub][3] - mnew);
            psum += (p0 + p1) + (p2 + p3);
            unsigned lo, hi;
            asm("v_cvt_pk_bf16_f32 %0, %1, %2" : "=v"(lo) : "v"(p0), "v"(p1));
            asm("v_cvt_pk_bf16_f32 %0, %1, %2" : "=v"(hi) : "v"(p2), "v"(p3));
            uint2 u;
            u.x = lo; u.y = hi;
            *(uint2*)&Plds[w][lr][sub * 16 + lg * 4] = u;
        }
        psum += __shfl_xor(psum, 16);
        psum += __shfl_xor(psum, 32);
        lsum = lsum * fac + psum;
        m = mnew;
        float fr[4];
#pragma unroll
        for (int r = 0; r < 4; ++r) fr[r] = __shfl(fac, lg * 4 + r);
#pragma unroll
        for (int dt = 0; dt < 4; ++dt)
#pragma unroll
            for (int r = 0; r < 4; ++r) oacc[dt][r] *= fr[r];
#pragma unroll
        for (int kk = 0; kk < 4; ++kk) {
            if (kv0 + kk * 32 <= qmax) {
                bf16x8 pf = ldb(&Plds[w][lr][kk * 32 + lg * 8]);
#pragma unroll
                for (int dt = 0; dt < 4; ++dt) {
                    bf16x8 vf = ldb(Vbase + (long)(dt * 16 + lr) * SEQ + kv0 + kk * 32 + lg * 8);
                    oacc[dt] = MFMA(pf, vf, oacc[dt]);
                }
            }
        }
    }
    float li[4];
#pragma unroll
    for (int r = 0; r < 4; ++r) li[r] = 1.f / __shfl(lsum, lg * 4 + r);
    u16* Op = Ob + (long)(b * SEQ + q0) * DM + h * DK;
#pragma unroll
    for (int dt = 0; dt < 4; ++dt)
#pragma unroll
        for (int r = 0; r < 4; ++r)
            Op[(long)(lg * 4 + r) * DM + dt * 16 + lr] = f2bf(oacc[dt][r] * li[r]);
}

extern "C" void kernel_launch(void* const* d_in, const int* in_sizes, int n_in,
                              void* d_out, int out_size, void* d_ws, size_t ws_size,
                              hipStream_t stream) {
    const float* x = (const float*)d_in[0];
    const float* Wq = (const float*)d_in[1];
    const float* Wk = (const float*)d_in[2];
    const float* Wv = (const float*)d_in[3];
    const float* Wo = (const float*)d_in[4];
    float* out = (float*)d_out;

    const int M = 2 * SEQ;  // 4096 rows
    char* p = (char*)d_ws;
    u16* xb = (u16*)p;      p += (size_t)M * DM * 2;          // 8 MB
    u16* WqbT = (u16*)p;    p += (size_t)DM * DM * 2;         // 2 MB
    u16* WkvT = (u16*)p;    p += (size_t)2 * DK * DM * 2;     // 256 KB (K rows then V rows)
    u16* WobT = (u16*)p;    p += (size_t)DM * DM * 2;         // 2 MB
    float* KVf = (float*)p; p += (size_t)M * 128 * 4;         // 2 MB (cols 0-63 K, 64-127 V)
    u16* Qb = (u16*)p;      p += (size_t)M * DM * 2;          // 8 MB
    u16* Kb = (u16*)p;      p += (size_t)M * DK * 2;          // 512 KB
    u16* VbT = (u16*)p;     p += (size_t)M * DK * 2;          // 512 KB
    u16* Ob = (u16*)p;      p += (size_t)M * DM * 2;          // 8 MB
    float* Qf = out;  // reuse d_out (16 MB fp32) as scratch for pre-RoPE Q

    // 1) convert inputs to bf16 (+ weight transposes)
    k_cvt_bf16<<<(M * DM / 4 + 255) / 256, 256, 0, stream>>>(x, xb, M * DM / 4);
    k_transpose<<<dim3(DM / 32, DM / 32), 256, 0, stream>>>(Wq, WqbT, DM, DM, DM);
    k_transpose<<<dim3(DK / 32, DM / 32), 256, 0, stream>>>(Wk, WkvT, DK, DM, DK);
    k_transpose<<<dim3(DK / 32, DM / 32), 256, 0, stream>>>(Wv, WkvT + (size_t)DK * DM, DK, DM, DK);
    k_transpose<<<dim3(DM / 32, DM / 32), 256, 0, stream>>>(Wo, WobT, DM, DM, DM);

    // 2) projections (K and V fused into one N=128 GEMM)
    k_gemm<<<dim3(DM / 64, M / 64), 256, 0, stream>>>(xb, WqbT, Qf, DM, DM);
    k_gemm<<<dim3(2, M / 64), 256, 0, stream>>>(xb, WkvT, KVf, 128, DM);

    // 3) RoPE + V transpose (to bf16)
    k_rope_q<<<(M * NH * 32) / 256, 256, 0, stream>>>(Qf, Qb);
    k_rope_k<<<(M * 32) / 256, 256, 0, stream>>>(KVf, Kb);
    for (int bb = 0; bb < 2; ++bb)
        k_transpose<<<dim3(DK / 32, SEQ / 32), 256, 0, stream>>>(
            KVf + (size_t)bb * SEQ * 128 + DK, VbT + (size_t)bb * DK * SEQ, 128, SEQ, DK);

    // 4) attention
    k_attn<<<dim3(SEQ / 64, NH, 2), 256, 0, stream>>>(Qb, Kb, VbT, Ob);

    // 5) output projection -> d_out
    k_gemm<<<dim3(DM / 64, M / 64), 256, 0, stream>>>(Ob, WobT, out, DM, DM);
}

// Round 3
// 232.266 us; speedup vs baseline: 1.5222x; 1.4384x over previous
//
#include <hip/hip_runtime.h>

#define DM 1024
#define NH 16
#define DK 64
#define SEQ 2048

typedef __attribute__((ext_vector_type(8))) __bf16 bf16x8;
typedef __attribute__((ext_vector_type(4))) float f32x4;
typedef __attribute__((ext_vector_type(16))) float f32x16;
typedef __attribute__((ext_vector_type(8))) unsigned short u16x8;
typedef __attribute__((ext_vector_type(4))) unsigned int u32x4;
typedef unsigned short u16;

#define MFMA(a, b, c) __builtin_amdgcn_mfma_f32_16x16x32_bf16(a, b, c, 0, 0, 0)
#define MFMA32(a, b, c) __builtin_amdgcn_mfma_f32_32x32x16_bf16(a, b, c, 0, 0, 0)

__device__ __forceinline__ u16 f2bf(float f) {
    unsigned u = __builtin_bit_cast(unsigned, f);
    u = (u + 0x7FFFu + ((u >> 16) & 1u)) >> 16;
    return (u16)u;
}

__device__ __forceinline__ bf16x8 ldb(const u16* p) {
    u16x8 v = *(const u16x8*)p;
    return __builtin_bit_cast(bf16x8, v);
}

__device__ __forceinline__ unsigned cvtpk(float a, float b) {
    unsigned r;
    asm("v_cvt_pk_bf16_f32 %0, %1, %2" : "=v"(r) : "v"(a), "v"(b));
    return r;
}

__device__ __forceinline__ void swap32(unsigned& a, unsigned& b) {
    asm volatile("v_permlane32_swap_b32 %0, %1" : "+v"(a), "+v"(b));
}

// ---------------- elementwise f32 -> bf16 (vectorized x4) ----------------
__global__ __launch_bounds__(256) void k_cvt_bf16(const float* __restrict__ in,
                                                  u16* __restrict__ out, int n4) {
    int i = blockIdx.x * 256 + threadIdx.x;
    if (i < n4) {
        float4 v = ((const float4*)in)[i];
        ushort4 o;
        o.x = f2bf(v.x); o.y = f2bf(v.y); o.z = f2bf(v.z); o.w = f2bf(v.w);
        ((ushort4*)out)[i] = o;
    }
}

// ------ tiled transpose + convert: W[K][ldW] (cols n0..) f32 -> WT[N][K] bf16 ------
__global__ __launch_bounds__(256) void k_transpose(const float* __restrict__ W,
                                                   u16* __restrict__ WT, int ldW,
                                                   int K, int N) {
    __shared__ float t[32][33];
    int n0 = blockIdx.x * 32, k0 = blockIdx.y * 32;
    int tx = threadIdx.x & 31, ty = threadIdx.x >> 5;
#pragma unroll
    for (int i = 0; i < 32; i += 8)
        t[ty + i][tx] = W[(long)(k0 + ty + i) * ldW + n0 + tx];
    __syncthreads();
#pragma unroll
    for (int i = 0; i < 32; i += 8)
        WT[(long)(n0 + ty + i) * K + k0 + tx] = f2bf(t[tx][ty + i]);
}

// ---------------- bf16 GEMM: C[M][N] f32 = A[M][K] * BT[N][K]^T ----------------
__global__ __launch_bounds__(256) void k_gemm(const u16* __restrict__ A,
                                              const u16* __restrict__ BT,
                                              float* __restrict__ C, int N, int K) {
    __shared__ __align__(16) u16 As[64][72];
    __shared__ __align__(16) u16 Bs[64][72];
    int tid = threadIdx.x;
    int w = tid >> 6, lane = tid & 63, lg = lane >> 4, lr = lane & 15;
    int wr = w >> 1, wc = w & 1;
    int m0 = blockIdx.y * 64, n0 = blockIdx.x * 64;
    f32x4 acc[2][2] = {};
    for (int k0 = 0; k0 < K; k0 += 64) {
#pragma unroll
        for (int i = 0; i < 2; ++i) {
            int q = tid + i * 256;
            int row = q >> 3, ch = (q & 7) * 8;
            *(u16x8*)&As[row][ch] = *(const u16x8*)(A + (long)(m0 + row) * K + k0 + ch);
            *(u16x8*)&Bs[row][ch] = *(const u16x8*)(BT + (long)(n0 + row) * K + k0 + ch);
        }
        __syncthreads();
#pragma unroll
        for (int kk = 0; kk < 64; kk += 32) {
            bf16x8 a0 = ldb(&As[wr * 32 + lr][kk + lg * 8]);
            bf16x8 a1 = ldb(&As[wr * 32 + 16 + lr][kk + lg * 8]);
            bf16x8 b0 = ldb(&Bs[wc * 32 + lr][kk + lg * 8]);
            bf16x8 b1 = ldb(&Bs[wc * 32 + 16 + lr][kk + lg * 8]);
            acc[0][0] = MFMA(a0, b0, acc[0][0]);
            acc[0][1] = MFMA(a0, b1, acc[0][1]);
            acc[1][0] = MFMA(a1, b0, acc[1][0]);
            acc[1][1] = MFMA(a1, b1, acc[1][1]);
        }
        __syncthreads();
    }
#pragma unroll
    for (int mi = 0; mi < 2; ++mi)
#pragma unroll
        for (int ni = 0; ni < 2; ++ni)
#pragma unroll
            for (int r = 0; r < 4; ++r) {
                int row = m0 + wr * 32 + mi * 16 + lg * 4 + r;
                int col = n0 + wc * 32 + ni * 16 + lr;
                C[(long)row * N + col] = acc[mi][ni][r];
            }
}

// ---------------- RoPE for Q: read f32, write bf16 ----------------
__global__ __launch_bounds__(256) void k_rope_q(const float* __restrict__ Qf,
                                                u16* __restrict__ Qb) {
    int idx = blockIdx.x * 256 + threadIdx.x;  // B*S*NH*32
    int i = idx & 31;
    int h = (idx >> 5) & 15;
    int r = idx >> 9;  // b*S + s
    int s = r & (SEQ - 1);
    float theta = exp2f(-(float)i * 0.4152410118609203f);  // 10000^(-2i/64)
    float ang = (float)s * theta;
    float sn, cs;
    sincosf(ang, &sn, &cs);
    const float* p = Qf + (long)r * DM + h * DK + 2 * i;
    float x1 = p[0], x2 = p[1];
    u16* o = Qb + (long)r * DM + h * DK + 2 * i;
    o[0] = f2bf(x1 * cs - x2 * sn);
    o[1] = f2bf(x2 * cs + x1 * sn);
}

// ---------------- RoPE for K (reads fused KV buffer, row stride 128) ----------------
__global__ __launch_bounds__(256) void k_rope_k(const float* __restrict__ KVf,
                                                u16* __restrict__ Kb) {
    int idx = blockIdx.x * 256 + threadIdx.x;  // B*S*32
    int i = idx & 31;
    int r = idx >> 5;  // b*S + s
    int s = r & (SEQ - 1);
    float theta = exp2f(-(float)i * 0.4152410118609203f);
    float ang = (float)s * theta;
    float sn, cs;
    sincosf(ang, &sn, &cs);
    const float* p = KVf + (long)r * 128 + 2 * i;
    float x1 = p[0], x2 = p[1];
    u16* o = Kb + (long)r * DK + 2 * i;
    o[0] = f2bf(x1 * cs - x2 * sn);
    o[1] = f2bf(x2 * cs + x1 * sn);
}

// ---------------- attention tile: 32 q-rows/wave, 64 kv (2 blocks of 32) ----------------
// Swapped QK^T: S^T[kv][q] = mfma(K, Q^T); lane owns q-col (lq), regs hold kv rows
// crow(r,hi) = (r&3) + 8*(r>>2) + 4*hi.  Swapped PV: O^T[d][q] = mfma(V^T, P^T).
template <bool HAS1, bool MASKED>
__device__ __forceinline__ void attn_tile(int kv0, int q, int lq, int hi,
                                          const u16* __restrict__ Kbase,
                                          const u16* __restrict__ Vbase,
                                          const bf16x8 qf[4],
                                          f32x16& o0, f32x16& o1,
                                          float& m, float& lsum) {
    const float SC = 0.18033688011112042f;  // 0.125 * log2(e)
    const u16* K0 = Kbase + (long)(kv0 + lq) * DK + hi * 8;
    f32x16 s0 = {}, s1 = {};
    __builtin_amdgcn_s_setprio(1);
#pragma unroll
    for (int ks = 0; ks < 4; ++ks) {
        s0 = MFMA32(ldb(K0 + ks * 16), qf[ks], s0);
        if (HAS1) s1 = MFMA32(ldb(K0 + 32 * DK + ks * 16), qf[ks], s1);
    }
    __builtin_amdgcn_s_setprio(0);
    float sv0[16], sv1[16];
    float tmax = -3e38f;
#pragma unroll
    for (int r = 0; r < 16; ++r) {
        int crow = (r & 3) + 8 * (r >> 2) + 4 * hi;
        float v0 = s0[r] * SC;
        if (MASKED && kv0 + crow > q) v0 = -3e38f;
        sv0[r] = v0;
        tmax = fmaxf(tmax, v0);
        if (HAS1) {
            float v1 = s1[r] * SC;
            if (MASKED && kv0 + 32 + crow > q) v1 = -3e38f;
            sv1[r] = v1;
            tmax = fmaxf(tmax, v1);
        }
    }
    tmax = fmaxf(tmax, __shfl_xor(tmax, 32));
    float mnew = fmaxf(m, tmax);
    float fac = exp2f(m - mnew);
    m = mnew;
    float p0[16], p1[16];
    float psum = 0.f;
#pragma unroll
    for (int r = 0; r < 16; ++r) {
        p0[r] = exp2f(sv0[r] - mnew);
        psum += p0[r];
        if (HAS1) {
            p1[r] = exp2f(sv1[r] - mnew);
            psum += p1[r];
        }
    }
    psum += __shfl_xor(psum, 32);
    lsum = lsum * fac + psum;
    o0 *= fac;
    o1 *= fac;
    // pack P into PV B-operand fragments (T12: cvt_pk + permlane32_swap)
    bf16x8 pa[4];
#pragma unroll
    for (int g = 0; g < 2; ++g) {
        unsigned a0 = cvtpk(p0[g * 8 + 0], p0[g * 8 + 1]);
        unsigned b0 = cvtpk(p0[g * 8 + 4], p0[g * 8 + 5]);
        swap32(a0, b0);
        unsigned a1 = cvtpk(p0[g * 8 + 2], p0[g * 8 + 3]);
        unsigned b1 = cvtpk(p0[g * 8 + 6], p0[g * 8 + 7]);
        swap32(a1, b1);
        u32x4 u = {a0, a1, b0, b1};
        pa[g] = __builtin_bit_cast(bf16x8, u);
    }
    if (HAS1) {
#pragma unroll
        for (int g = 0; g < 2; ++g) {
            unsigned a0 = cvtpk(p1[g * 8 + 0], p1[g * 8 + 1]);
            unsigned b0 = cvtpk(p1[g * 8 + 4], p1[g * 8 + 5]);
            swap32(a0, b0);
            unsigned a1 = cvtpk(p1[g * 8 + 2], p1[g * 8 + 3]);
            unsigned b1 = cvtpk(p1[g * 8 + 6], p1[g * 8 + 7]);
            swap32(a1, b1);
            u32x4 u = {a0, a1, b0, b1};
            pa[2 + g] = __builtin_bit_cast(bf16x8, u);
        }
    }
    const u16* V0 = Vbase + (long)lq * SEQ + kv0 + hi * 8;
    const long VD = (long)32 * SEQ;
    __builtin_amdgcn_s_setprio(1);
#pragma unroll
    for (int ks = 0; ks < (HAS1 ? 4 : 2); ++ks) {
        o0 = MFMA32(ldb(V0 + ks * 16), pa[ks], o0);
        o1 = MFMA32(ldb(V0 + VD + ks * 16), pa[ks], o1);
    }
    __builtin_amdgcn_s_setprio(0);
}

// grid: (SEQ/128, NH, B), 256 threads = 4 waves x 32 q-rows. K/V from global (L2).
__global__ __launch_bounds__(256) void k_attn(const u16* __restrict__ Qb,
                                              const u16* __restrict__ Kb,
                                              const u16* __restrict__ VbT,
                                              u16* __restrict__ Ob) {
    __shared__ __align__(16) u16 Ot[4][32][72];
    int b = blockIdx.z, h = blockIdx.y;
    int w = threadIdx.x >> 6, lane = threadIdx.x & 63;
    int lq = lane & 31, hi = lane >> 5;
    int q0w = (gridDim.x - 1 - blockIdx.x) * 128 + w * 32;
    int q = q0w + lq;
    const u16* Qp = Qb + (long)(b * SEQ + q) * DM + h * DK + hi * 8;
    bf16x8 qf[4];
#pragma unroll
    for (int ks = 0; ks < 4; ++ks) qf[ks] = ldb(Qp + ks * 16);
    const u16* Kbase = Kb + (long)b * SEQ * DK;
    const u16* Vbase = VbT + (long)b * DK * SEQ;
    f32x16 o0 = {}, o1 = {};
    float m = -1e30f, lsum = 0.f;

    int kv0 = 0;
    for (; kv0 + 64 <= q0w; kv0 += 64)
        attn_tile<true, false>(kv0, q, lq, hi, Kbase, Vbase, qf, o0, o1, m, lsum);
    // tail: tile containing the diagonal
    if (q0w & 32)
        attn_tile<true, true>(q0w & ~63, q, lq, hi, Kbase, Vbase, qf, o0, o1, m, lsum);
    else
        attn_tile<false, true>(q0w, q, lq, hi, Kbase, Vbase, qf, o0, o1, m, lsum);

    float linv = 1.f / lsum;
    // O^T regs -> LDS transpose -> coalesced global store
#pragma unroll
    for (int rq = 0; rq < 4; ++rq) {
        uint2 u0, u1;
        u0.x = cvtpk(o0[4 * rq + 0] * linv, o0[4 * rq + 1] * linv);
        u0.y = cvtpk(o0[4 * rq + 2] * linv, o0[4 * rq + 3] * linv);
        u1.x = cvtpk(o1[4 * rq + 0] * linv, o1[4 * rq + 1] * linv);
        u1.y = cvtpk(o1[4 * rq + 2] * linv, o1[4 * rq + 3] * linv);
        *(uint2*)&Ot[w][lq][rq * 8 + hi * 4] = u0;
        *(uint2*)&Ot[w][lq][32 + rq * 8 + hi * 4] = u1;
    }
#pragma unroll
    for (int i = 0; i < 4; ++i) {
        int c = i * 64 + lane;
        int row = c >> 3, col = (c & 7) * 8;
        u16x8 v = *(const u16x8*)&Ot[w][row][col];
        *(u16x8*)(Ob + (long)(b * SEQ + q0w + row) * DM + h * DK + col) = v;
    }
}

extern "C" void kernel_launch(void* const* d_in, const int* in_sizes, int n_in,
                              void* d_out, int out_size, void* d_ws, size_t ws_size,
                              hipStream_t stream) {
    const float* x = (const float*)d_in[0];
    const float* Wq = (const float*)d_in[1];
    const float* Wk = (const float*)d_in[2];
    const float* Wv = (const float*)d_in[3];
    const float* Wo = (const float*)d_in[4];
    float* out = (float*)d_out;

    const int M = 2 * SEQ;  // 4096 rows
    char* p = (char*)d_ws;
    u16* xb = (u16*)p;      p += (size_t)M * DM * 2;          // 8 MB
    u16* WqbT = (u16*)p;    p += (size_t)DM * DM * 2;         // 2 MB
    u16* WkvT = (u16*)p;    p += (size_t)2 * DK * DM * 2;     // 256 KB (K rows then V rows)
    u16* WobT = (u16*)p;    p += (size_t)DM * DM * 2;         // 2 MB
    float* KVf = (float*)p; p += (size_t)M * 128 * 4;         // 2 MB (cols 0-63 K, 64-127 V)
    u16* Qb = (u16*)p;      p += (size_t)M * DM * 2;          // 8 MB
    u16* Kb = (u16*)p;      p += (size_t)M * DK * 2;          // 512 KB
    u16* VbT = (u16*)p;     p += (size_t)M * DK * 2;          // 512 KB
    u16* Ob = (u16*)p;      p += (size_t)M * DM * 2;          // 8 MB
    float* Qf = out;  // reuse d_out (16 MB fp32) as scratch for pre-RoPE Q

    // 1) convert inputs to bf16 (+ weight transposes)
    k_cvt_bf16<<<(M * DM / 4 + 255) / 256, 256, 0, stream>>>(x, xb, M * DM / 4);
    k_transpose<<<dim3(DM / 32, DM / 32), 256, 0, stream>>>(Wq, WqbT, DM, DM, DM);
    k_transpose<<<dim3(DK / 32, DM / 32), 256, 0, stream>>>(Wk, WkvT, DK, DM, DK);
    k_transpose<<<dim3(DK / 32, DM / 32), 256, 0, stream>>>(Wv, WkvT + (size_t)DK * DM, DK, DM, DK);
    k_transpose<<<dim3(DM / 32, DM / 32), 256, 0, stream>>>(Wo, WobT, DM, DM, DM);

    // 2) projections (K and V fused into one N=128 GEMM)
    k_gemm<<<dim3(DM / 64, M / 64), 256, 0, stream>>>(xb, WqbT, Qf, DM, DM);
    k_gemm<<<dim3(2, M / 64), 256, 0, stream>>>(xb, WkvT, KVf, 128, DM);

    // 3) RoPE + V transpose (to bf16)
    k_rope_q<<<(M * NH * 32) / 256, 256, 0, stream>>>(Qf, Qb);
    k_rope_k<<<(M * 32) / 256, 256, 0, stream>>>(KVf, Kb);
    for (int bb = 0; bb < 2; ++bb)
        k_transpose<<<dim3(DK / 32, SEQ / 32), 256, 0, stream>>>(
            KVf + (size_t)bb * SEQ * 128 + DK, VbT + (size_t)bb * DK * SEQ, 128, SEQ, DK);

    // 4) attention (32x32 swapped-operand, in-register softmax)
    k_attn<<<dim3(SEQ / 128, NH, 2), 256, 0, stream>>>(Qb, Kb, VbT, Ob);

    // 5) output projection -> d_out
    k_gemm<<<dim3(DM / 64, M / 64), 256, 0, stream>>>(Ob, WobT, out, DM, DM);
}

// Round 4
// 217.147 us; speedup vs baseline: 1.6282x; 1.0696x over previous
//
#include <hip/hip_runtime.h>

#define DM 1024
#define NH 16
#define DK 64
#define SEQ 2048

typedef __attribute__((ext_vector_type(8))) __bf16 bf16x8;
typedef __attribute__((ext_vector_type(4))) float f32x4;
typedef __attribute__((ext_vector_type(16))) float f32x16;
typedef __attribute__((ext_vector_type(8))) unsigned short u16x8;
typedef __attribute__((ext_vector_type(4))) unsigned int u32x4;
typedef unsigned short u16;

#define MFMA(a, b, c) __builtin_amdgcn_mfma_f32_16x16x32_bf16(a, b, c, 0, 0, 0)
#define MFMA32(a, b, c) __builtin_amdgcn_mfma_f32_32x32x16_bf16(a, b, c, 0, 0, 0)

__device__ __forceinline__ u16 f2bf(float f) {
    unsigned u = __builtin_bit_cast(unsigned, f);
    u = (u + 0x7FFFu + ((u >> 16) & 1u)) >> 16;
    return (u16)u;
}

__device__ __forceinline__ bf16x8 ldb(const u16* p) {
    u16x8 v = *(const u16x8*)p;
    return __builtin_bit_cast(bf16x8, v);
}

__device__ __forceinline__ unsigned cvtpk(float a, float b) {
    unsigned r;
    asm("v_cvt_pk_bf16_f32 %0, %1, %2" : "=v"(r) : "v"(a), "v"(b));
    return r;
}

__device__ __forceinline__ void swap32(unsigned& a, unsigned& b) {
    asm volatile("v_permlane32_swap_b32 %0, %1" : "+v"(a), "+v"(b));
}

// async global->LDS, 16B per lane, LDS dest = wave-uniform base + lane*16
__device__ __forceinline__ void gload16(const u16* g, u16* l) {
    __builtin_amdgcn_global_load_lds(
        (const __attribute__((address_space(1))) unsigned int*)g,
        (__attribute__((address_space(3))) unsigned int*)l, 16, 0, 0);
}

// ---------------- elementwise f32 -> bf16 (vectorized x4) ----------------
__global__ __launch_bounds__(256) void k_cvt_bf16(const float* __restrict__ in,
                                                  u16* __restrict__ out, int n4) {
    int i = blockIdx.x * 256 + threadIdx.x;
    if (i < n4) {
        float4 v = ((const float4*)in)[i];
        ushort4 o;
        o.x = f2bf(v.x); o.y = f2bf(v.y); o.z = f2bf(v.z); o.w = f2bf(v.w);
        ((ushort4*)out)[i] = o;
    }
}

// ------ tiled transpose + convert: W[K][ldW] (cols n0..) f32 -> WT[N][K] bf16 ------
__global__ __launch_bounds__(256) void k_transpose(const float* __restrict__ W,
                                                   u16* __restrict__ WT, int ldW,
                                                   int K, int N) {
    __shared__ float t[32][33];
    int n0 = blockIdx.x * 32, k0 = blockIdx.y * 32;
    int tx = threadIdx.x & 31, ty = threadIdx.x >> 5;
#pragma unroll
    for (int i = 0; i < 32; i += 8)
        t[ty + i][tx] = W[(long)(k0 + ty + i) * ldW + n0 + tx];
    __syncthreads();
#pragma unroll
    for (int i = 0; i < 32; i += 8)
        WT[(long)(n0 + ty + i) * K + k0 + tx] = f2bf(t[tx][ty + i]);
}

// ---- bf16 GEMM (m97 structure): C[M][N] f32 = A[M][K] * BT[N][K]^T ----
// 128x128 tile, BK=64, 256 thr = 4 waves; global_load_lds width-16 staging.
__global__ __launch_bounds__(256) void k_gemm128(const u16* __restrict__ A,
                                                 const u16* __restrict__ BT,
                                                 float* __restrict__ C, int N, int K) {
    __shared__ __align__(16) u16 As[128 * 64];
    __shared__ __align__(16) u16 Bs[128 * 64];
    int tid = threadIdx.x;
    int w = tid >> 6, lane = tid & 63, lg = lane >> 4, lr = lane & 15;
    int wr = w >> 1, wc = w & 1;
    int m0 = blockIdx.y * 128, n0 = blockIdx.x * 128;
    int lrow = lane >> 3, lcol = (lane & 7) * 8;
    f32x4 acc[4][4] = {};
    for (int k0 = 0; k0 < K; k0 += 64) {
#pragma unroll
        for (int it = 0; it < 4; ++it) {
            int row = w * 32 + it * 8;
            gload16(A + (long)(m0 + row + lrow) * K + k0 + lcol, &As[row * 64]);
            gload16(BT + (long)(n0 + row + lrow) * K + k0 + lcol, &Bs[row * 64]);
        }
        __syncthreads();
#pragma unroll
        for (int kk = 0; kk < 64; kk += 32) {
            bf16x8 af[4], bf[4];
#pragma unroll
            for (int i = 0; i < 4; ++i) {
                af[i] = ldb(&As[(wr * 64 + i * 16 + lr) * 64 + kk + lg * 8]);
                bf[i] = ldb(&Bs[(wc * 64 + i * 16 + lr) * 64 + kk + lg * 8]);
            }
#pragma unroll
            for (int mi = 0; mi < 4; ++mi)
#pragma unroll
                for (int ni = 0; ni < 4; ++ni)
                    acc[mi][ni] = MFMA(af[mi], bf[ni], acc[mi][ni]);
        }
        __syncthreads();
    }
#pragma unroll
    for (int mi = 0; mi < 4; ++mi)
#pragma unroll
        for (int ni = 0; ni < 4; ++ni)
#pragma unroll
            for (int r = 0; r < 4; ++r) {
                int row = m0 + wr * 64 + mi * 16 + lg * 4 + r;
                int col = n0 + wc * 64 + ni * 16 + lr;
                C[(long)row * N + col] = acc[mi][ni][r];
            }
}

// ---------------- RoPE for Q: read f32, write bf16 scaled by 0.125*log2e ----------------
__global__ __launch_bounds__(256) void k_rope_q(const float* __restrict__ Qf,
                                                u16* __restrict__ Qb) {
    const float SC = 0.18033688011112042f;  // 0.125 * log2(e), folded into Q
    int idx = blockIdx.x * 256 + threadIdx.x;  // B*S*NH*32
    int i = idx & 31;
    int h = (idx >> 5) & 15;
    int r = idx >> 9;  // b*S + s
    int s = r & (SEQ - 1);
    float theta = exp2f(-(float)i * 0.4152410118609203f);  // 10000^(-2i/64)
    float ang = (float)s * theta;
    float sn, cs;
    sincosf(ang, &sn, &cs);
    const float* p = Qf + (long)r * DM + h * DK + 2 * i;
    float x1 = p[0], x2 = p[1];
    u16* o = Qb + (long)r * DM + h * DK + 2 * i;
    o[0] = f2bf((x1 * cs - x2 * sn) * SC);
    o[1] = f2bf((x2 * cs + x1 * sn) * SC);
}

// ---------------- RoPE for K (reads fused KV buffer, row stride 128) ----------------
__global__ __launch_bounds__(256) void k_rope_k(const float* __restrict__ KVf,
                                                u16* __restrict__ Kb) {
    int idx = blockIdx.x * 256 + threadIdx.x;  // B*S*32
    int i = idx & 31;
    int r = idx >> 5;  // b*S + s
    int s = r & (SEQ - 1);
    float theta = exp2f(-(float)i * 0.4152410118609203f);
    float ang = (float)s * theta;
    float sn, cs;
    sincosf(ang, &sn, &cs);
    const float* p = KVf + (long)r * 128 + 2 * i;
    float x1 = p[0], x2 = p[1];
    u16* o = Kb + (long)r * DK + 2 * i;
    o[0] = f2bf(x1 * cs - x2 * sn);
    o[1] = f2bf(x2 * cs + x1 * sn);
}

// ---------------- attention: 1 wave, 32 q-rows, 64-kv tiles, reg-pipelined ----------------
struct Kregs { bf16x8 k[8]; };
struct Vregs { bf16x8 v[8]; };

__device__ __forceinline__ void loadK(Kregs& R, const u16* Kbase, int kv0, int lq, int hi) {
    const u16* K0 = Kbase + (long)(kv0 + lq) * DK + hi * 8;
#pragma unroll
    for (int ks = 0; ks < 4; ++ks) {
        R.k[ks] = ldb(K0 + ks * 16);
        R.k[4 + ks] = ldb(K0 + 32 * DK + ks * 16);  // 2nd half may over-read (benign, unused)
    }
}
__device__ __forceinline__ void loadV(Vregs& R, const u16* Vbase, int kv0, int lq, int hi) {
    const u16* V0 = Vbase + (long)lq * SEQ + kv0 + hi * 8;
#pragma unroll
    for (int ks = 0; ks < 4; ++ks) {
        R.v[ks] = ldb(V0 + ks * 16);
        R.v[4 + ks] = ldb(V0 + (long)32 * SEQ + ks * 16);
    }
}

// Swapped QK^T: S^T[kv][q] = mfma(K, Q^T); crow(r,hi) = (r&3) + 8*(r>>2) + 4*hi.
// Swapped PV: O^T[d][q] = mfma(V^T, P^T). Softmax in log2 domain, deferred max.
template <bool HAS1, bool MASKED>
__device__ __forceinline__ void attn_tile(int kv0, int q, int hi,
                                          const Kregs& K, const Vregs& V,
                                          const bf16x8 qf[4],
                                          f32x16& o0, f32x16& o1,
                                          float& m, float& lsum) {
    f32x16 s0 = {}, s1 = {};
    __builtin_amdgcn_s_setprio(1);
#pragma unroll
    for (int ks = 0; ks < 4; ++ks) {
        s0 = MFMA32(K.k[ks], qf[ks], s0);
        if (HAS1) s1 = MFMA32(K.k[4 + ks], qf[ks], s1);
    }
    __builtin_amdgcn_s_setprio(0);
    float sv0[16], sv1[16];
#pragma unroll
    for (int r = 0; r < 16; ++r) {
        int crow = (r & 3) + 8 * (r >> 2) + 4 * hi;
        float v0 = s0[r];
        if (MASKED && kv0 + crow > q) v0 = -3e38f;
        sv0[r] = v0;
        if (HAS1) {
            float v1 = s1[r];
            if (MASKED && kv0 + 32 + crow > q) v1 = -3e38f;
            sv1[r] = v1;
        }
    }
    // tree max (depth ~5 instead of 32-deep linear chain)
    float t[8];
#pragma unroll
    for (int j = 0; j < 8; ++j) {
        float a = fmaxf(sv0[j], sv0[j + 8]);
        if (HAS1) a = fmaxf(a, fmaxf(sv1[j], sv1[j + 8]));
        t[j] = a;
    }
    float pmax = fmaxf(fmaxf(fmaxf(t[0], t[4]), fmaxf(t[1], t[5])),
                       fmaxf(fmaxf(t[2], t[6]), fmaxf(t[3], t[7])));
    pmax = fmaxf(pmax, __shfl_xor(pmax, 32));
    // deferred-max rescale (T13): skip when max grew < 8 (log2 domain, P <= 256)
    if (__any(pmax > m + 8.f)) {
        float mnew = fmaxf(m, pmax);
        float fac = exp2f(m - mnew);
        m = mnew;
        lsum *= fac;
        o0 *= fac;
        o1 *= fac;
    }
    float p0[16], p1[16];
#pragma unroll
    for (int r = 0; r < 16; ++r) {
        p0[r] = exp2f(sv0[r] - m);
        if (HAS1) p1[r] = exp2f(sv1[r] - m);
    }
    // tree sum
    float s[8];
#pragma unroll
    for (int j = 0; j < 8; ++j) {
        float a = p0[j] + p0[j + 8];
        if (HAS1) a += p1[j] + p1[j + 8];
        s[j] = a;
    }
    float psum = ((s[0] + s[4]) + (s[1] + s[5])) + ((s[2] + s[6]) + (s[3] + s[7]));
    psum += __shfl_xor(psum, 32);
    lsum += psum;
    // pack P into PV B-operand fragments (T12: cvt_pk + permlane32_swap)
    bf16x8 pa[4];
#pragma unroll
    for (int g = 0; g < 2; ++g) {
        unsigned a0 = cvtpk(p0[g * 8 + 0], p0[g * 8 + 1]);
        unsigned b0 = cvtpk(p0[g * 8 + 4], p0[g * 8 + 5]);
        swap32(a0, b0);
        unsigned a1 = cvtpk(p0[g * 8 + 2], p0[g * 8 + 3]);
        unsigned b1 = cvtpk(p0[g * 8 + 6], p0[g * 8 + 7]);
        swap32(a1, b1);
        u32x4 u = {a0, a1, b0, b1};
        pa[g] = __builtin_bit_cast(bf16x8, u);
    }
    if (HAS1) {
#pragma unroll
        for (int g = 0; g < 2; ++g) {
            unsigned a0 = cvtpk(p1[g * 8 + 0], p1[g * 8 + 1]);
            unsigned b0 = cvtpk(p1[g * 8 + 4], p1[g * 8 + 5]);
            swap32(a0, b0);
            unsigned a1 = cvtpk(p1[g * 8 + 2], p1[g * 8 + 3]);
            unsigned b1 = cvtpk(p1[g * 8 + 6], p1[g * 8 + 7]);
            swap32(a1, b1);
            u32x4 u = {a0, a1, b0, b1};
            pa[2 + g] = __builtin_bit_cast(bf16x8, u);
        }
    }
    __builtin_amdgcn_s_setprio(1);
#pragma unroll
    for (int ks = 0; ks < (HAS1 ? 4 : 2); ++ks) {
        o0 = MFMA32(V.v[ks], pa[ks], o0);
        o1 = MFMA32(V.v[4 + ks], pa[ks], o1);
    }
    __builtin_amdgcn_s_setprio(0);
}

// grid: (SEQ/32, NH, B), 64 threads = 1 wave per block (no barriers anywhere).
__global__ __launch_bounds__(64) void k_attn(const u16* __restrict__ Qb,
                                             const u16* __restrict__ Kb,
                                             const u16* __restrict__ VbT,
                                             u16* __restrict__ Ob) {
    __shared__ __align__(16) u16 Ot[32][72];
    int b = blockIdx.z, h = blockIdx.y;
    int lane = threadIdx.x;
    int lq = lane & 31, hi = lane >> 5;
    int q0 = (gridDim.x - 1 - blockIdx.x) * 32;  // longest causal loops launch first
    int q = q0 + lq;
    const u16* Qp = Qb + (long)(b * SEQ + q) * DM + h * DK + hi * 8;
    bf16x8 qf[4];
#pragma unroll
    for (int ks = 0; ks < 4; ++ks) qf[ks] = ldb(Qp + ks * 16);
    const u16* Kbase = Kb + (long)b * SEQ * DK;
    const u16* Vbase = VbT + (long)b * DK * SEQ;
    f32x16 o0 = {}, o1 = {};
    float m = -1e30f, lsum = 0.f;

    int nt = (q0 >> 6) + 1;          // 64-kv tiles covering [0, q0+32)
    bool tail64 = (q0 & 32) != 0;    // last tile is 64 wide (masked) vs 32 wide
    Kregs KA, KB;
    Vregs Vc;
    loadK(KA, Kbase, 0, lq, hi);
    int i = 0;
    while (true) {
        loadV(Vc, Vbase, i * 64, lq, hi);
        if (i + 1 < nt) loadK(KB, Kbase, (i + 1) * 64, lq, hi);
        if (i == nt - 1) {
            if (tail64) attn_tile<true, true>(i * 64, q, hi, KA, Vc, qf, o0, o1, m, lsum);
            else        attn_tile<false, true>(i * 64, q, hi, KA, Vc, qf, o0, o1, m, lsum);
            break;
        }
        attn_tile<true, false>(i * 64, q, hi, KA, Vc, qf, o0, o1, m, lsum);
        ++i;
        loadV(Vc, Vbase, i * 64, lq, hi);
        if (i + 1 < nt) loadK(KA, Kbase, (i + 1) * 64, lq, hi);
        if (i == nt - 1) {
            if (tail64) attn_tile<true, true>(i * 64, q, hi, KB, Vc, qf, o0, o1, m, lsum);
            else        attn_tile<false, true>(i * 64, q, hi, KB, Vc, qf, o0, o1, m, lsum);
            break;
        }
        attn_tile<true, false>(i * 64, q, hi, KB, Vc, qf, o0, o1, m, lsum);
        ++i;
    }

    float linv = 1.f / lsum;
    // O^T regs -> LDS transpose -> coalesced global store
#pragma unroll
    for (int rq = 0; rq < 4; ++rq) {
        uint2 u0, u1;
        u0.x = cvtpk(o0[4 * rq + 0] * linv, o0[4 * rq + 1] * linv);
        u0.y = cvtpk(o0[4 * rq + 2] * linv, o0[4 * rq + 3] * linv);
        u1.x = cvtpk(o1[4 * rq + 0] * linv, o1[4 * rq + 1] * linv);
        u1.y = cvtpk(o1[4 * rq + 2] * linv, o1[4 * rq + 3] * linv);
        *(uint2*)&Ot[lq][rq * 8 + hi * 4] = u0;
        *(uint2*)&Ot[lq][32 + rq * 8 + hi * 4] = u1;
    }
#pragma unroll
    for (int i2 = 0; i2 < 4; ++i2) {
        int c = i2 * 64 + lane;
        int row = c >> 3, col = (c & 7) * 8;
        u16x8 v = *(const u16x8*)&Ot[row][col];
        *(u16x8*)(Ob + (long)(b * SEQ + q0 + row) * DM + h * DK + col) = v;
    }
}

extern "C" void kernel_launch(void* const* d_in, const int* in_sizes, int n_in,
                              void* d_out, int out_size, void* d_ws, size_t ws_size,
                              hipStream_t stream) {
    const float* x = (const float*)d_in[0];
    const float* Wq = (const float*)d_in[1];
    const float* Wk = (const float*)d_in[2];
    const float* Wv = (const float*)d_in[3];
    const float* Wo = (const float*)d_in[4];
    float* out = (float*)d_out;

    const int M = 2 * SEQ;  // 4096 rows
    char* p = (char*)d_ws;
    u16* xb = (u16*)p;      p += (size_t)M * DM * 2;          // 8 MB
    u16* WqbT = (u16*)p;    p += (size_t)DM * DM * 2;         // 2 MB
    u16* WkvT = (u16*)p;    p += (size_t)2 * DK * DM * 2;     // 256 KB (K rows then V rows)
    u16* WobT = (u16*)p;    p += (size_t)DM * DM * 2;         // 2 MB
    float* KVf = (float*)p; p += (size_t)M * 128 * 4;         // 2 MB (cols 0-63 K, 64-127 V)
    u16* Qb = (u16*)p;      p += (size_t)M * DM * 2;          // 8 MB
    u16* Kb = (u16*)p;      p += (size_t)M * DK * 2;          // 512 KB
    u16* VbT = (u16*)p;     p += (size_t)M * DK * 2;          // 512 KB
    u16* Ob = (u16*)p;      p += (size_t)M * DM * 2;          // 8 MB
    float* Qf = out;  // reuse d_out (16 MB fp32) as scratch for pre-RoPE Q

    // 1) convert inputs to bf16 (+ weight transposes)
    k_cvt_bf16<<<(M * DM / 4 + 255) / 256, 256, 0, stream>>>(x, xb, M * DM / 4);
    k_transpose<<<dim3(DM / 32, DM / 32), 256, 0, stream>>>(Wq, WqbT, DM, DM, DM);
    k_transpose<<<dim3(DK / 32, DM / 32), 256, 0, stream>>>(Wk, WkvT, DK, DM, DK);
    k_transpose<<<dim3(DK / 32, DM / 32), 256, 0, stream>>>(Wv, WkvT + (size_t)DK * DM, DK, DM, DK);
    k_transpose<<<dim3(DM / 32, DM / 32), 256, 0, stream>>>(Wo, WobT, DM, DM, DM);

    // 2) projections (128x128-tile GEMM w/ global_load_lds; K,V fused as N=128)
    k_gemm128<<<dim3(DM / 128, M / 128), 256, 0, stream>>>(xb, WqbT, Qf, DM, DM);
    k_gemm128<<<dim3(1, M / 128), 256, 0, stream>>>(xb, WkvT, KVf, 128, DM);

    // 3) RoPE + V transpose (to bf16)
    k_rope_q<<<(M * NH * 32) / 256, 256, 0, stream>>>(Qf, Qb);
    k_rope_k<<<(M * 32) / 256, 256, 0, stream>>>(KVf, Kb);
    for (int bb = 0; bb < 2; ++bb)
        k_transpose<<<dim3(DK / 32, SEQ / 32), 256, 0, stream>>>(
            KVf + (size_t)bb * SEQ * 128 + DK, VbT + (size_t)bb * DK * SEQ, 128, SEQ, DK);

    // 4) attention (1-wave blocks, reg-pipelined, deferred-max)
    k_attn<<<dim3(SEQ / 32, NH, 2), 64, 0, stream>>>(Qb, Kb, VbT, Ob);

    // 5) output projection -> d_out
    k_gemm128<<<dim3(DM / 128, M / 128), 256, 0, stream>>>(Ob, WobT, out, DM, DM);
}

// Round 5
// 189.209 us; speedup vs baseline: 1.8686x; 1.1477x over previous
//
#include <hip/hip_runtime.h>

#define DM 1024
#define NH 16
#define DK 64
#define SEQ 2048

typedef __attribute__((ext_vector_type(8))) __bf16 bf16x8;
typedef __attribute__((ext_vector_type(4))) float f32x4;
typedef __attribute__((ext_vector_type(16))) float f32x16;
typedef __attribute__((ext_vector_type(8))) unsigned short u16x8;
typedef __attribute__((ext_vector_type(4))) unsigned int u32x4;
typedef unsigned short u16;

#define MFMA(a, b, c) __builtin_amdgcn_mfma_f32_16x16x32_bf16(a, b, c, 0, 0, 0)
#define MFMA32(a, b, c) __builtin_amdgcn_mfma_f32_32x32x16_bf16(a, b, c, 0, 0, 0)

__device__ __forceinline__ u16 f2bf(float f) {
    unsigned u = __builtin_bit_cast(unsigned, f);
    u = (u + 0x7FFFu + ((u >> 16) & 1u)) >> 16;
    return (u16)u;
}

__device__ __forceinline__ bf16x8 ldb(const u16* p) {
    u16x8 v = *(const u16x8*)p;
    return __builtin_bit_cast(bf16x8, v);
}

__device__ __forceinline__ unsigned cvtpk(float a, float b) {
    unsigned r;
    asm("v_cvt_pk_bf16_f32 %0, %1, %2" : "=v"(r) : "v"(a), "v"(b));
    return r;
}

__device__ __forceinline__ void swap32(unsigned& a, unsigned& b) {
    asm volatile("v_permlane32_swap_b32 %0, %1" : "+v"(a), "+v"(b));
}

// async global->LDS, 16B per lane, LDS dest = wave-uniform base + lane*16
__device__ __forceinline__ void gload16(const u16* g, u16* l) {
    __builtin_amdgcn_global_load_lds(
        (const __attribute__((address_space(1))) unsigned int*)g,
        (__attribute__((address_space(3))) unsigned int*)l, 16, 0, 0);
}

// ---------------- elementwise f32 -> bf16 (vectorized x4) ----------------
__global__ __launch_bounds__(256) void k_cvt_bf16(const float* __restrict__ in,
                                                  u16* __restrict__ out, int n4) {
    int i = blockIdx.x * 256 + threadIdx.x;
    if (i < n4) {
        float4 v = ((const float4*)in)[i];
        ushort4 o;
        o.x = f2bf(v.x); o.y = f2bf(v.y); o.z = f2bf(v.z); o.w = f2bf(v.w);
        ((ushort4*)out)[i] = o;
    }
}

// ------ tiled transpose + convert: W[K][ldW] (cols n0..) f32 -> WT[N][K] bf16 ------
__global__ __launch_bounds__(256) void k_transpose(const float* __restrict__ W,
                                                   u16* __restrict__ WT, int ldW,
                                                   int K, int N) {
    __shared__ float t[32][33];
    int n0 = blockIdx.x * 32, k0 = blockIdx.y * 32;
    int tx = threadIdx.x & 31, ty = threadIdx.x >> 5;
#pragma unroll
    for (int i = 0; i < 32; i += 8)
        t[ty + i][tx] = W[(long)(k0 + ty + i) * ldW + n0 + tx];
    __syncthreads();
#pragma unroll
    for (int i = 0; i < 32; i += 8)
        WT[(long)(n0 + ty + i) * K + k0 + tx] = f2bf(t[tx][ty + i]);
}

// ---- bf16 GEMM (m97 structure): C[M][N] f32 = A[M][K] * BT[N][K]^T ----
// 128x128 tile, BK=64, 256 thr = 4 waves; global_load_lds width-16 staging.
__global__ __launch_bounds__(256) void k_gemm128(const u16* __restrict__ A,
                                                 const u16* __restrict__ BT,
                                                 float* __restrict__ C, int N, int K) {
    __shared__ __align__(16) u16 As[128 * 64];
    __shared__ __align__(16) u16 Bs[128 * 64];
    int tid = threadIdx.x;
    int w = tid >> 6, lane = tid & 63, lg = lane >> 4, lr = lane & 15;
    int wr = w >> 1, wc = w & 1;
    int m0 = blockIdx.y * 128, n0 = blockIdx.x * 128;
    int lrow = lane >> 3, lcol = (lane & 7) * 8;
    f32x4 acc[4][4] = {};
    for (int k0 = 0; k0 < K; k0 += 64) {
#pragma unroll
        for (int it = 0; it < 4; ++it) {
            int row = w * 32 + it * 8;
            gload16(A + (long)(m0 + row + lrow) * K + k0 + lcol, &As[row * 64]);
            gload16(BT + (long)(n0 + row + lrow) * K + k0 + lcol, &Bs[row * 64]);
        }
        __syncthreads();
#pragma unroll
        for (int kk = 0; kk < 64; kk += 32) {
            bf16x8 af[4], bf[4];
#pragma unroll
            for (int i = 0; i < 4; ++i) {
                af[i] = ldb(&As[(wr * 64 + i * 16 + lr) * 64 + kk + lg * 8]);
                bf[i] = ldb(&Bs[(wc * 64 + i * 16 + lr) * 64 + kk + lg * 8]);
            }
#pragma unroll
            for (int mi = 0; mi < 4; ++mi)
#pragma unroll
                for (int ni = 0; ni < 4; ++ni)
                    acc[mi][ni] = MFMA(af[mi], bf[ni], acc[mi][ni]);
        }
        __syncthreads();
    }
#pragma unroll
    for (int mi = 0; mi < 4; ++mi)
#pragma unroll
        for (int ni = 0; ni < 4; ++ni)
#pragma unroll
            for (int r = 0; r < 4; ++r) {
                int row = m0 + wr * 64 + mi * 16 + lg * 4 + r;
                int col = n0 + wc * 64 + ni * 16 + lr;
                C[(long)row * N + col] = acc[mi][ni][r];
            }
}

// ---------------- RoPE for Q: read f32, write bf16 scaled by 0.125*log2e ----------------
__global__ __launch_bounds__(256) void k_rope_q(const float* __restrict__ Qf,
                                                u16* __restrict__ Qb) {
    const float SC = 0.18033688011112042f;  // 0.125 * log2(e), folded into Q
    int idx = blockIdx.x * 256 + threadIdx.x;  // B*S*NH*32
    int i = idx & 31;
    int h = (idx >> 5) & 15;
    int r = idx >> 9;  // b*S + s
    int s = r & (SEQ - 1);
    float theta = exp2f(-(float)i * 0.4152410118609203f);  // 10000^(-2i/64)
    float ang = (float)s * theta;
    float sn, cs;
    sincosf(ang, &sn, &cs);
    const float* p = Qf + (long)r * DM + h * DK + 2 * i;
    float x1 = p[0], x2 = p[1];
    u16* o = Qb + (long)r * DM + h * DK + 2 * i;
    o[0] = f2bf((x1 * cs - x2 * sn) * SC);
    o[1] = f2bf((x2 * cs + x1 * sn) * SC);
}

// ---------------- RoPE for K (reads fused KV buffer, row stride 128) ----------------
__global__ __launch_bounds__(256) void k_rope_k(const float* __restrict__ KVf,
                                                u16* __restrict__ Kb) {
    int idx = blockIdx.x * 256 + threadIdx.x;  // B*S*32
    int i = idx & 31;
    int r = idx >> 5;  // b*S + s
    int s = r & (SEQ - 1);
    float theta = exp2f(-(float)i * 0.4152410118609203f);
    float ang = (float)s * theta;
    float sn, cs;
    sincosf(ang, &sn, &cs);
    const float* p = KVf + (long)r * 128 + 2 * i;
    float x1 = p[0], x2 = p[1];
    u16* o = Kb + (long)r * DK + 2 * i;
    o[0] = f2bf(x1 * cs - x2 * sn);
    o[1] = f2bf(x2 * cs + x1 * sn);
}

// ---------------- attention: 1 wave, 32 q-rows, 64-kv tiles, reg-pipelined ----------------
struct Kregs { bf16x8 k[8]; };
struct Vregs { bf16x8 v[8]; };

__device__ __forceinline__ void loadK(Kregs& R, const u16* Kbase, int kv0, int lq, int hi) {
    const u16* K0 = Kbase + (long)(kv0 + lq) * DK + hi * 8;
#pragma unroll
    for (int ks = 0; ks < 4; ++ks) {
        R.k[ks] = ldb(K0 + ks * 16);
        R.k[4 + ks] = ldb(K0 + 32 * DK + ks * 16);  // 2nd half may over-read (benign, unused)
    }
}
__device__ __forceinline__ void loadV(Vregs& R, const u16* Vbase, int kv0, int lq, int hi) {
    const u16* V0 = Vbase + (long)lq * SEQ + kv0 + hi * 8;
#pragma unroll
    for (int ks = 0; ks < 4; ++ks) {
        R.v[ks] = ldb(V0 + ks * 16);
        R.v[4 + ks] = ldb(V0 + (long)32 * SEQ + ks * 16);
    }
}

// Swapped QK^T: S^T[kv][q] = mfma(K, Q^T); crow(r,hi) = (r&3) + 8*(r>>2) + 4*hi.
// Swapped PV: O^T[d][q] = mfma(V^T, P^T). Softmax in log2 domain, deferred max.
template <bool HAS1, bool MASKED>
__device__ __forceinline__ void attn_tile(int kv0, int q, int hi,
                                          const Kregs& K, const Vregs& V,
                                          const bf16x8 qf[4],
                                          f32x16& o0, f32x16& o1,
                                          float& m, float& lsum) {
    f32x16 s0 = {}, s1 = {};
    __builtin_amdgcn_s_setprio(1);
#pragma unroll
    for (int ks = 0; ks < 4; ++ks) {
        s0 = MFMA32(K.k[ks], qf[ks], s0);
        if (HAS1) s1 = MFMA32(K.k[4 + ks], qf[ks], s1);
    }
    __builtin_amdgcn_s_setprio(0);
    float sv0[16], sv1[16];
#pragma unroll
    for (int r = 0; r < 16; ++r) {
        int crow = (r & 3) + 8 * (r >> 2) + 4 * hi;
        float v0 = s0[r];
        if (MASKED && kv0 + crow > q) v0 = -3e38f;
        sv0[r] = v0;
        if (HAS1) {
            float v1 = s1[r];
            if (MASKED && kv0 + 32 + crow > q) v1 = -3e38f;
            sv1[r] = v1;
        }
    }
    // tree max (depth ~5 instead of 32-deep linear chain)
    float t[8];
#pragma unroll
    for (int j = 0; j < 8; ++j) {
        float a = fmaxf(sv0[j], sv0[j + 8]);
        if (HAS1) a = fmaxf(a, fmaxf(sv1[j], sv1[j + 8]));
        t[j] = a;
    }
    float pmax = fmaxf(fmaxf(fmaxf(t[0], t[4]), fmaxf(t[1], t[5])),
                       fmaxf(fmaxf(t[2], t[6]), fmaxf(t[3], t[7])));
    pmax = fmaxf(pmax, __shfl_xor(pmax, 32));
    // deferred-max rescale (T13): skip when max grew < 8 (log2 domain, P <= 256)
    if (__any(pmax > m + 8.f)) {
        float mnew = fmaxf(m, pmax);
        float fac = exp2f(m - mnew);
        m = mnew;
        lsum *= fac;
        o0 *= fac;
        o1 *= fac;
    }
    float p0[16], p1[16];
#pragma unroll
    for (int r = 0; r < 16; ++r) {
        p0[r] = exp2f(sv0[r] - m);
        if (HAS1) p1[r] = exp2f(sv1[r] - m);
    }
    // tree sum
    float s[8];
#pragma unroll
    for (int j = 0; j < 8; ++j) {
        float a = p0[j] + p0[j + 8];
        if (HAS1) a += p1[j] + p1[j + 8];
        s[j] = a;
    }
    float psum = ((s[0] + s[4]) + (s[1] + s[5])) + ((s[2] + s[6]) + (s[3] + s[7]));
    psum += __shfl_xor(psum, 32);
    lsum += psum;
    // pack P into PV B-operand fragments (T12: cvt_pk + permlane32_swap)
    bf16x8 pa[4];
#pragma unroll
    for (int g = 0; g < 2; ++g) {
        unsigned a0 = cvtpk(p0[g * 8 + 0], p0[g * 8 + 1]);
        unsigned b0 = cvtpk(p0[g * 8 + 4], p0[g * 8 + 5]);
        swap32(a0, b0);
        unsigned a1 = cvtpk(p0[g * 8 + 2], p0[g * 8 + 3]);
        unsigned b1 = cvtpk(p0[g * 8 + 6], p0[g * 8 + 7]);
        swap32(a1, b1);
        u32x4 u = {a0, a1, b0, b1};
        pa[g] = __builtin_bit_cast(bf16x8, u);
    }
    if (HAS1) {
#pragma unroll
        for (int g = 0; g < 2; ++g) {
            unsigned a0 = cvtpk(p1[g * 8 + 0], p1[g * 8 + 1]);
            unsigned b0 = cvtpk(p1[g * 8 + 4], p1[g * 8 + 5]);
            swap32(a0, b0);
            unsigned a1 = cvtpk(p1[g * 8 + 2], p1[g * 8 + 3]);
            unsigned b1 = cvtpk(p1[g * 8 + 6], p1[g * 8 + 7]);
            swap32(a1, b1);
            u32x4 u = {a0, a1, b0, b1};
            pa[2 + g] = __builtin_bit_cast(bf16x8, u);
        }
    }
    __builtin_amdgcn_s_setprio(1);
#pragma unroll
    for (int ks = 0; ks < (HAS1 ? 4 : 2); ++ks) {
        o0 = MFMA32(V.v[ks], pa[ks], o0);
        o1 = MFMA32(V.v[4 + ks], pa[ks], o1);
    }
    __builtin_amdgcn_s_setprio(0);
}

// grid: flat 2048 blocks, 64 threads = 1 wave (no barriers anywhere).
// Work-mixing decode: (h,b) in the fast 5 bits so co-resident blocks on a CU
// get qt values spread stride-8 across [0,64); qt = 37*qslot mod 64 (bijective)
// mixes long and short causal loops uniformly across CUs.
__global__ __launch_bounds__(64) void k_attn(const u16* __restrict__ Qb,
                                             const u16* __restrict__ Kb,
                                             const u16* __restrict__ VbT,
                                             u16* __restrict__ Ob) {
    __shared__ __align__(16) u16 Ot[32][72];
    int id = blockIdx.x;
    int h = id & 15, b = (id >> 4) & 1;
    int qslot = id >> 5;
    int qt = (qslot * 37) & 63;
    int q0 = qt * 32;
    int lane = threadIdx.x;
    int lq = lane & 31, hi = lane >> 5;
    int q = q0 + lq;
    const u16* Qp = Qb + (long)(b * SEQ + q) * DM + h * DK + hi * 8;
    bf16x8 qf[4];
#pragma unroll
    for (int ks = 0; ks < 4; ++ks) qf[ks] = ldb(Qp + ks * 16);
    const u16* Kbase = Kb + (long)b * SEQ * DK;
    const u16* Vbase = VbT + (long)b * DK * SEQ;
    f32x16 o0 = {}, o1 = {};
    float m = -1e30f, lsum = 0.f;

    int nt = (q0 >> 6) + 1;          // 64-kv tiles covering [0, q0+32)
    bool tail64 = (q0 & 32) != 0;    // last tile is 64 wide (masked) vs 32 wide
    Kregs KA, KB;
    Vregs Vc;
    loadK(KA, Kbase, 0, lq, hi);
    int i = 0;
    while (true) {
        loadV(Vc, Vbase, i * 64, lq, hi);
        if (i + 1 < nt) loadK(KB, Kbase, (i + 1) * 64, lq, hi);
        if (i == nt - 1) {
            if (tail64) attn_tile<true, true>(i * 64, q, hi, KA, Vc, qf, o0, o1, m, lsum);
            else        attn_tile<false, true>(i * 64, q, hi, KA, Vc, qf, o0, o1, m, lsum);
            break;
        }
        attn_tile<true, false>(i * 64, q, hi, KA, Vc, qf, o0, o1, m, lsum);
        ++i;
        loadV(Vc, Vbase, i * 64, lq, hi);
        if (i + 1 < nt) loadK(KA, Kbase, (i + 1) * 64, lq, hi);
        if (i == nt - 1) {
            if (tail64) attn_tile<true, true>(i * 64, q, hi, KB, Vc, qf, o0, o1, m, lsum);
            else        attn_tile<false, true>(i * 64, q, hi, KB, Vc, qf, o0, o1, m, lsum);
            break;
        }
        attn_tile<true, false>(i * 64, q, hi, KB, Vc, qf, o0, o1, m, lsum);
        ++i;
    }

    float linv = 1.f / lsum;
    // O^T regs -> LDS transpose -> coalesced global store
#pragma unroll
    for (int rq = 0; rq < 4; ++rq) {
        uint2 u0, u1;
        u0.x = cvtpk(o0[4 * rq + 0] * linv, o0[4 * rq + 1] * linv);
        u0.y = cvtpk(o0[4 * rq + 2] * linv, o0[4 * rq + 3] * linv);
        u1.x = cvtpk(o1[4 * rq + 0] * linv, o1[4 * rq + 1] * linv);
        u1.y = cvtpk(o1[4 * rq + 2] * linv, o1[4 * rq + 3] * linv);
        *(uint2*)&Ot[lq][rq * 8 + hi * 4] = u0;
        *(uint2*)&Ot[lq][32 + rq * 8 + hi * 4] = u1;
    }
#pragma unroll
    for (int i2 = 0; i2 < 4; ++i2) {
        int c = i2 * 64 + lane;
        int row = c >> 3, col = (c & 7) * 8;
        u16x8 v = *(const u16x8*)&Ot[row][col];
        *(u16x8*)(Ob + (long)(b * SEQ + q0 + row) * DM + h * DK + col) = v;
    }
}

extern "C" void kernel_launch(void* const* d_in, const int* in_sizes, int n_in,
                              void* d_out, int out_size, void* d_ws, size_t ws_size,
                              hipStream_t stream) {
    const float* x = (const float*)d_in[0];
    const float* Wq = (const float*)d_in[1];
    const float* Wk = (const float*)d_in[2];
    const float* Wv = (const float*)d_in[3];
    const float* Wo = (const float*)d_in[4];
    float* out = (float*)d_out;

    const int M = 2 * SEQ;  // 4096 rows
    char* p = (char*)d_ws;
    u16* xb = (u16*)p;      p += (size_t)M * DM * 2;          // 8 MB
    u16* WqbT = (u16*)p;    p += (size_t)DM * DM * 2;         // 2 MB
    u16* WkvT = (u16*)p;    p += (size_t)2 * DK * DM * 2;     // 256 KB (K rows then V rows)
    u16* WobT = (u16*)p;    p += (size_t)DM * DM * 2;         // 2 MB
    float* KVf = (float*)p; p += (size_t)M * 128 * 4;         // 2 MB (cols 0-63 K, 64-127 V)
    u16* Qb = (u16*)p;      p += (size_t)M * DM * 2;          // 8 MB
    u16* Kb = (u16*)p;      p += (size_t)M * DK * 2;          // 512 KB
    u16* VbT = (u16*)p;     p += (size_t)M * DK * 2;          // 512 KB
    u16* Ob = (u16*)p;      p += (size_t)M * DM * 2;          // 8 MB
    float* Qf = out;  // reuse d_out (16 MB fp32) as scratch for pre-RoPE Q

    // 1) convert inputs to bf16 (+ weight transposes)
    k_cvt_bf16<<<(M * DM / 4 + 255) / 256, 256, 0, stream>>>(x, xb, M * DM / 4);
    k_transpose<<<dim3(DM / 32, DM / 32), 256, 0, stream>>>(Wq, WqbT, DM, DM, DM);
    k_transpose<<<dim3(DK / 32, DM / 32), 256, 0, stream>>>(Wk, WkvT, DK, DM, DK);
    k_transpose<<<dim3(DK / 32, DM / 32), 256, 0, stream>>>(Wv, WkvT + (size_t)DK * DM, DK, DM, DK);
    k_transpose<<<dim3(DM / 32, DM / 32), 256, 0, stream>>>(Wo, WobT, DM, DM, DM);

    // 2) projections (128x128-tile GEMM w/ global_load_lds; K,V fused as N=128)
    k_gemm128<<<dim3(DM / 128, M / 128), 256, 0, stream>>>(xb, WqbT, Qf, DM, DM);
    k_gemm128<<<dim3(1, M / 128), 256, 0, stream>>>(xb, WkvT, KVf, 128, DM);

    // 3) RoPE + V transpose (to bf16)
    k_rope_q<<<(M * NH * 32) / 256, 256, 0, stream>>>(Qf, Qb);
    k_rope_k<<<(M * 32) / 256, 256, 0, stream>>>(KVf, Kb);
    for (int bb = 0; bb < 2; ++bb)
        k_transpose<<<dim3(DK / 32, SEQ / 32), 256, 0, stream>>>(
            KVf + (size_t)bb * SEQ * 128 + DK, VbT + (size_t)bb * DK * SEQ, 128, SEQ, DK);

    // 4) attention (1-wave blocks, work-mixed flat grid, deferred-max)
    k_attn<<<dim3(2 * NH * (SEQ / 32)), 64, 0, stream>>>(Qb, Kb, VbT, Ob);

    // 5) output projection -> d_out
    k_gemm128<<<dim3(DM / 128, M / 128), 256, 0, stream>>>(Ob, WobT, out, DM, DM);
}

// Round 7
// 157.878 us; speedup vs baseline: 2.2395x; 1.1985x over previous
//
#include <hip/hip_runtime.h>

#define DM 1024
#define NH 16
#define DK 64
#define SEQ 2048

typedef __attribute__((ext_vector_type(8))) __bf16 bf16x8;
typedef __attribute__((ext_vector_type(4))) float f32x4;
typedef __attribute__((ext_vector_type(16))) float f32x16;
typedef __attribute__((ext_vector_type(8))) unsigned short u16x8;
typedef __attribute__((ext_vector_type(4))) unsigned int u32x4;
typedef unsigned short u16;

#define MFMA(a, b, c) __builtin_amdgcn_mfma_f32_16x16x32_bf16(a, b, c, 0, 0, 0)
#define MFMA32(a, b, c) __builtin_amdgcn_mfma_f32_32x32x16_bf16(a, b, c, 0, 0, 0)

__device__ __forceinline__ u16 f2bf(float f) {
    unsigned u = __builtin_bit_cast(unsigned, f);
    u = (u + 0x7FFFu + ((u >> 16) & 1u)) >> 16;
    return (u16)u;
}

__device__ __forceinline__ bf16x8 ldb(const u16* p) {
    u16x8 v = *(const u16x8*)p;
    return __builtin_bit_cast(bf16x8, v);
}

__device__ __forceinline__ unsigned cvtpk(float a, float b) {
    unsigned r;
    asm("v_cvt_pk_bf16_f32 %0, %1, %2" : "=v"(r) : "v"(a), "v"(b));
    return r;
}

__device__ __forceinline__ void swap32(unsigned& a, unsigned& b) {
    asm volatile("v_permlane32_swap_b32 %0, %1" : "+v"(a), "+v"(b));
}

// async global->LDS, 16B per lane, LDS dest = wave-uniform base + lane*16
__device__ __forceinline__ void gload16(const u16* g, u16* l) {
    __builtin_amdgcn_global_load_lds(
        (const __attribute__((address_space(1))) unsigned int*)g,
        (__attribute__((address_space(3))) unsigned int*)l, 16, 0, 0);
}

// ---------------- elementwise f32 -> bf16 (vectorized x4) ----------------
__global__ __launch_bounds__(256) void k_cvt_bf16(const float* __restrict__ in,
                                                  u16* __restrict__ out, int n4) {
    int i = blockIdx.x * 256 + threadIdx.x;
    if (i < n4) {
        float4 v = ((const float4*)in)[i];
        ushort4 o;
        o.x = f2bf(v.x); o.y = f2bf(v.y); o.z = f2bf(v.z); o.w = f2bf(v.w);
        ((ushort4*)out)[i] = o;
    }
}

// ------ tiled transpose + convert: W[K][ldW] (cols n0..) f32 -> WT[N][K] bf16 ------
__global__ __launch_bounds__(256) void k_transpose(const float* __restrict__ W,
                                                   u16* __restrict__ WT, int ldW,
                                                   int K, int N) {
    __shared__ float t[32][33];
    int n0 = blockIdx.x * 32, k0 = blockIdx.y * 32;
    int tx = threadIdx.x & 31, ty = threadIdx.x >> 5;
#pragma unroll
    for (int i = 0; i < 32; i += 8)
        t[ty + i][tx] = W[(long)(k0 + ty + i) * ldW + n0 + tx];
    __syncthreads();
#pragma unroll
    for (int i = 0; i < 32; i += 8)
        WT[(long)(n0 + ty + i) * K + k0 + tx] = f2bf(t[tx][ty + i]);
}

// ---- bf16 GEMM (m97 structure): C[M][N] f32 = A[M][K] * BT[N][K]^T ----
__global__ __launch_bounds__(256) void k_gemm128(const u16* __restrict__ A,
                                                 const u16* __restrict__ BT,
                                                 float* __restrict__ C, int N, int K) {
    __shared__ __align__(16) u16 As[128 * 64];
    __shared__ __align__(16) u16 Bs[128 * 64];
    int tid = threadIdx.x;
    int w = tid >> 6, lane = tid & 63, lg = lane >> 4, lr = lane & 15;
    int wr = w >> 1, wc = w & 1;
    int m0 = blockIdx.y * 128, n0 = blockIdx.x * 128;
    int lrow = lane >> 3, lcol = (lane & 7) * 8;
    f32x4 acc[4][4] = {};
    for (int k0 = 0; k0 < K; k0 += 64) {
#pragma unroll
        for (int it = 0; it < 4; ++it) {
            int row = w * 32 + it * 8;
            gload16(A + (long)(m0 + row + lrow) * K + k0 + lcol, &As[row * 64]);
            gload16(BT + (long)(n0 + row + lrow) * K + k0 + lcol, &Bs[row * 64]);
        }
        __syncthreads();
#pragma unroll
        for (int kk = 0; kk < 64; kk += 32) {
            bf16x8 af[4], bf[4];
#pragma unroll
            for (int i = 0; i < 4; ++i) {
                af[i] = ldb(&As[(wr * 64 + i * 16 + lr) * 64 + kk + lg * 8]);
                bf[i] = ldb(&Bs[(wc * 64 + i * 16 + lr) * 64 + kk + lg * 8]);
            }
#pragma unroll
            for (int mi = 0; mi < 4; ++mi)
#pragma unroll
                for (int ni = 0; ni < 4; ++ni)
                    acc[mi][ni] = MFMA(af[mi], bf[ni], acc[mi][ni]);
        }
        __syncthreads();
    }
#pragma unroll
    for (int mi = 0; mi < 4; ++mi)
#pragma unroll
        for (int ni = 0; ni < 4; ++ni)
#pragma unroll
            for (int r = 0; r < 4; ++r) {
                int row = m0 + wr * 64 + mi * 16 + lg * 4 + r;
                int col = n0 + wc * 64 + ni * 16 + lr;
                C[(long)row * N + col] = acc[mi][ni][r];
            }
}

// ---------------- RoPE for Q: read f32, write bf16 scaled by 0.125*log2e ----------------
__global__ __launch_bounds__(256) void k_rope_q(const float* __restrict__ Qf,
                                                u16* __restrict__ Qb) {
    const float SC = 0.18033688011112042f;  // 0.125 * log2(e), folded into Q
    int idx = blockIdx.x * 256 + threadIdx.x;  // B*S*NH*32
    int i = idx & 31;
    int h = (idx >> 5) & 15;
    int r = idx >> 9;  // b*S + s
    int s = r & (SEQ - 1);
    float theta = exp2f(-(float)i * 0.4152410118609203f);  // 10000^(-2i/64)
    float ang = (float)s * theta;
    float sn, cs;
    sincosf(ang, &sn, &cs);
    const float* p = Qf + (long)r * DM + h * DK + 2 * i;
    float x1 = p[0], x2 = p[1];
    u16* o = Qb + (long)r * DM + h * DK + 2 * i;
    o[0] = f2bf((x1 * cs - x2 * sn) * SC);
    o[1] = f2bf((x2 * cs + x1 * sn) * SC);
}

// ---------------- RoPE for K (reads fused KV buffer, row stride 128) ----------------
__global__ __launch_bounds__(256) void k_rope_k(const float* __restrict__ KVf,
                                                u16* __restrict__ Kb) {
    int idx = blockIdx.x * 256 + threadIdx.x;  // B*S*32
    int i = idx & 31;
    int r = idx >> 5;  // b*S + s
    int s = r & (SEQ - 1);
    float theta = exp2f(-(float)i * 0.4152410118609203f);
    float ang = (float)s * theta;
    float sn, cs;
    sincosf(ang, &sn, &cs);
    const float* p = KVf + (long)r * 128 + 2 * i;
    float x1 = p[0], x2 = p[1];
    u16* o = Kb + (long)r * DK + 2 * i;
    o[0] = f2bf(x1 * cs - x2 * sn);
    o[1] = f2bf(x2 * cs + x1 * sn);
}

// ============ attention: 4 waves x 32 q-rows, LDS-staged K/V, XOR-swizzled ============
// LDS tile = [64 rows][64 bf16] (128B rows). Swizzle: 16B slot ^= (row&7).
// Staging (rule #21): linear LDS dest, inverse-swizzled GLOBAL source per lane.
// stage2: wave w stages passes {w, w+4}; pass p = rows 8p..8p+7 (1KB each).
__device__ __forceinline__ void stage2(u16* dst, const u16* src0, long rstride,
                                       int w, int lane) {
#pragma unroll
    for (int pp = 0; pp < 2; ++pp) {
        int p = w + pp * 4;
        int row = p * 8 + (lane >> 3), slot = lane & 7;
        gload16(src0 + (long)row * rstride + ((slot ^ (row & 7)) * 8), dst + p * 512);
    }
}

// swizzled fragment read: logical (row, 16B-slot) -> 8 bf16
__device__ __forceinline__ bf16x8 lds_frag(const u16* tile, int row, int slot) {
    return ldb(tile + row * 64 + ((slot ^ (row & 7)) * 8));
}

// Swapped QK^T: S^T[kv][q] = mfma(K, Q^T); crow(r,hi) = (r&3) + 8*(r>>2) + 4*hi.
// Swapped PV: O^T[d][q] = mfma(V^T, P^T). log2-domain softmax, deferred max (T13).
template <bool MASKED>
__device__ __forceinline__ void attn_tile(int kv0, int q, int lq, int hi,
                                          const u16* Kt, const u16* Vt,
                                          const bf16x8 qf[4],
                                          f32x16& o0, f32x16& o1,
                                          float& m, float& lsum) {
    f32x16 s0 = {}, s1 = {};
    __builtin_amdgcn_s_setprio(1);
#pragma unroll
    for (int ks = 0; ks < 4; ++ks) {
        s0 = MFMA32(lds_frag(Kt, lq, hi + 2 * ks), qf[ks], s0);
        s1 = MFMA32(lds_frag(Kt, lq + 32, hi + 2 * ks), qf[ks], s1);
    }
    __builtin_amdgcn_s_setprio(0);
    if (MASKED) {
#pragma unroll
        for (int r = 0; r < 16; ++r) {
            int crow = (r & 3) + 8 * (r >> 2) + 4 * hi;
            if (kv0 + crow > q) s0[r] = -3e38f;
            if (kv0 + 32 + crow > q) s1[r] = -3e38f;
        }
    }
    // tree max
    float t[8];
#pragma unroll
    for (int j = 0; j < 8; ++j)
        t[j] = fmaxf(fmaxf(s0[j], s0[j + 8]), fmaxf(s1[j], s1[j + 8]));
    float pmax = fmaxf(fmaxf(fmaxf(t[0], t[4]), fmaxf(t[1], t[5])),
                       fmaxf(fmaxf(t[2], t[6]), fmaxf(t[3], t[7])));
    pmax = fmaxf(pmax, __shfl_xor(pmax, 32));
    if (__any(pmax > m + 8.f)) {
        float mnew = fmaxf(m, pmax);
        float fac = exp2f(m - mnew);
        m = mnew;
        lsum *= fac;
        o0 *= fac;
        o1 *= fac;
    }
    float p0[16], p1[16];
#pragma unroll
    for (int r = 0; r < 16; ++r) {
        p0[r] = exp2f(s0[r] - m);
        p1[r] = exp2f(s1[r] - m);
    }
    // tree sum
    float su[8];
#pragma unroll
    for (int j = 0; j < 8; ++j)
        su[j] = (p0[j] + p0[j + 8]) + (p1[j] + p1[j + 8]);
    float psum = ((su[0] + su[4]) + (su[1] + su[5])) + ((su[2] + su[6]) + (su[3] + su[7]));
    psum += __shfl_xor(psum, 32);
    lsum += psum;
    // pack P into PV B-operand fragments (T12: cvt_pk + permlane32_swap)
    bf16x8 pa[4];
#pragma unroll
    for (int g = 0; g < 2; ++g) {
        unsigned a0 = cvtpk(p0[g * 8 + 0], p0[g * 8 + 1]);
        unsigned b0 = cvtpk(p0[g * 8 + 4], p0[g * 8 + 5]);
        swap32(a0, b0);
        unsigned a1 = cvtpk(p0[g * 8 + 2], p0[g * 8 + 3]);
        unsigned b1 = cvtpk(p0[g * 8 + 6], p0[g * 8 + 7]);
        swap32(a1, b1);
        u32x4 u = {a0, a1, b0, b1};
        pa[g] = __builtin_bit_cast(bf16x8, u);
    }
#pragma unroll
    for (int g = 0; g < 2; ++g) {
        unsigned a0 = cvtpk(p1[g * 8 + 0], p1[g * 8 + 1]);
        unsigned b0 = cvtpk(p1[g * 8 + 4], p1[g * 8 + 5]);
        swap32(a0, b0);
        unsigned a1 = cvtpk(p1[g * 8 + 2], p1[g * 8 + 3]);
        unsigned b1 = cvtpk(p1[g * 8 + 6], p1[g * 8 + 7]);
        swap32(a1, b1);
        u32x4 u = {a0, a1, b0, b1};
        pa[2 + g] = __builtin_bit_cast(bf16x8, u);
    }
    __builtin_amdgcn_s_setprio(1);
#pragma unroll
    for (int ks = 0; ks < 4; ++ks) {
        o0 = MFMA32(lds_frag(Vt, lq, hi + 2 * ks), pa[ks], o0);
        o1 = MFMA32(lds_frag(Vt, lq + 32, hi + 2 * ks), pa[ks], o1);
    }
    __builtin_amdgcn_s_setprio(0);
}

// grid: flat 512 blocks (256 thr = 4 waves, 128 q-rows). 2 blocks/CU; the qslot
// permutation makes co-resident pairs' trip counts sum to a constant (15+4 tiles).
__global__ __launch_bounds__(256) void k_attn(const u16* __restrict__ Qb,
                                              const u16* __restrict__ Kb,
                                              const u16* __restrict__ VbT,
                                              u16* __restrict__ Ob) {
    __shared__ __align__(16) u16 lds[2][2][4096];  // [buf][K/V][64x64 bf16]
    int id = blockIdx.x;
    int h = id & 15, b = (id >> 4) & 1;
    int qslot = id >> 5;                               // 0..15
    int qt = qslot < 8 ? qslot * 2 : 31 - qslot * 2;   // pair-balanced bijection
    int qb0 = qt * 128;
    int w = threadIdx.x >> 6, lane = threadIdx.x & 63;
    int lq = lane & 31, hi = lane >> 5;
    int q0w = qb0 + 32 * w;
    int q = q0w + lq;
    const u16* Qp = Qb + (long)(b * SEQ + q) * DM + h * DK + hi * 8;
    bf16x8 qf[4];
#pragma unroll
    for (int ks = 0; ks < 4; ++ks) qf[ks] = ldb(Qp + ks * 16);
    const u16* Kbase = Kb + (long)b * SEQ * DK;
    const u16* Vbase = VbT + (long)b * DK * SEQ;
    f32x16 o0 = {}, o1 = {};
    float m = -1e30f, lsum = 0.f;

    int nt = (qb0 >> 6) + 2;  // 64-kv tiles covering [0, qb0+128)
    stage2(&lds[0][0][0], Kbase, DK, w, lane);
    stage2(&lds[0][1][0], Vbase, SEQ, w, lane);
    __syncthreads();
    int buf = 0;
    for (int t = 0; t < nt; ++t) {
        int kv0 = t * 64;
        if (t + 1 < nt) {
            stage2(&lds[buf ^ 1][0][0], Kbase + (long)(kv0 + 64) * DK, DK, w, lane);
            stage2(&lds[buf ^ 1][1][0], Vbase + kv0 + 64, SEQ, w, lane);
        }
        if (kv0 <= q0w + 31) {
            if (kv0 + 63 <= q0w)
                attn_tile<false>(kv0, q, lq, hi, &lds[buf][0][0], &lds[buf][1][0],
                                 qf, o0, o1, m, lsum);
            else
                attn_tile<true>(kv0, q, lq, hi, &lds[buf][0][0], &lds[buf][1][0],
                                qf, o0, o1, m, lsum);
        }
        __syncthreads();
        buf ^= 1;
    }

    float linv = 1.f / lsum;
    // O^T regs -> LDS transpose (reuse staging LDS; barrier above guarantees done)
    u16* Ot = &lds[0][0][0] + w * 2304;  // 32 x 72 u16 per wave
#pragma unroll
    for (int rq = 0; rq < 4; ++rq) {
        uint2 u0, u1;
        u0.x = cvtpk(o0[4 * rq + 0] * linv, o0[4 * rq + 1] * linv);
        u0.y = cvtpk(o0[4 * rq + 2] * linv, o0[4 * rq + 3] * linv);
        u1.x = cvtpk(o1[4 * rq + 0] * linv, o1[4 * rq + 1] * linv);
        u1.y = cvtpk(o1[4 * rq + 2] * linv, o1[4 * rq + 3] * linv);
        *(uint2*)&Ot[lq * 72 + rq * 8 + hi * 4] = u0;
        *(uint2*)&Ot[lq * 72 + 32 + rq * 8 + hi * 4] = u1;
    }
#pragma unroll
    for (int i2 = 0; i2 < 4; ++i2) {
        int c = i2 * 64 + lane;
        int row = c >> 3, col = (c & 7) * 8;
        u16x8 v = *(const u16x8*)&Ot[row * 72 + col];
        *(u16x8*)(Ob + (long)(b * SEQ + q0w + row) * DM + h * DK + col) = v;
    }
}

extern "C" void kernel_launch(void* const* d_in, const int* in_sizes, int n_in,
                              void* d_out, int out_size, void* d_ws, size_t ws_size,
                              hipStream_t stream) {
    const float* x = (const float*)d_in[0];
    const float* Wq = (const float*)d_in[1];
    const float* Wk = (const float*)d_in[2];
    const float* Wv = (const float*)d_in[3];
    const float* Wo = (const float*)d_in[4];
    float* out = (float*)d_out;

    const int M = 2 * SEQ;  // 4096 rows
    char* p = (char*)d_ws;
    u16* xb = (u16*)p;      p += (size_t)M * DM * 2;          // 8 MB
    u16* WqbT = (u16*)p;    p += (size_t)DM * DM * 2;         // 2 MB
    u16* WkvT = (u16*)p;    p += (size_t)2 * DK * DM * 2;     // 256 KB (K rows then V rows)
    u16* WobT = (u16*)p;    p += (size_t)DM * DM * 2;         // 2 MB
    float* KVf = (float*)p; p += (size_t)M * 128 * 4;         // 2 MB (cols 0-63 K, 64-127 V)
    u16* Qb = (u16*)p;      p += (size_t)M * DM * 2;          // 8 MB
    u16* Kb = (u16*)p;      p += (size_t)M * DK * 2;          // 512 KB
    u16* VbT = (u16*)p;     p += (size_t)M * DK * 2;          // 512 KB
    u16* Ob = (u16*)p;      p += (size_t)M * DM * 2;          // 8 MB
    float* Qf = out;  // reuse d_out (16 MB fp32) as scratch for pre-RoPE Q

    // 1) convert inputs to bf16 (+ weight transposes)
    k_cvt_bf16<<<(M * DM / 4 + 255) / 256, 256, 0, stream>>>(x, xb, M * DM / 4);
    k_transpose<<<dim3(DM / 32, DM / 32), 256, 0, stream>>>(Wq, WqbT, DM, DM, DM);
    k_transpose<<<dim3(DK / 32, DM / 32), 256, 0, stream>>>(Wk, WkvT, DK, DM, DK);
    k_transpose<<<dim3(DK / 32, DM / 32), 256, 0, stream>>>(Wv, WkvT + (size_t)DK * DM, DK, DM, DK);
    k_transpose<<<dim3(DM / 32, DM / 32), 256, 0, stream>>>(Wo, WobT, DM, DM, DM);

    // 2) projections (128x128-tile GEMM w/ global_load_lds; K,V fused as N=128)
    k_gemm128<<<dim3(DM / 128, M / 128), 256, 0, stream>>>(xb, WqbT, Qf, DM, DM);
    k_gemm128<<<dim3(1, M / 128), 256, 0, stream>>>(xb, WkvT, KVf, 128, DM);

    // 3) RoPE + V transpose (to bf16)
    k_rope_q<<<(M * NH * 32) / 256, 256, 0, stream>>>(Qf, Qb);
    k_rope_k<<<(M * 32) / 256, 256, 0, stream>>>(KVf, Kb);
    for (int bb = 0; bb < 2; ++bb)
        k_transpose<<<dim3(DK / 32, SEQ / 32), 256, 0, stream>>>(
            KVf + (size_t)bb * SEQ * 128 + DK, VbT + (size_t)bb * DK * SEQ, 128, SEQ, DK);

    // 4) attention (4-wave blocks, LDS-staged K/V, pair-balanced grid)
    k_attn<<<dim3(2 * NH * (SEQ / 128)), 256, 0, stream>>>(Qb, Kb, VbT, Ob);

    // 5) output projection -> d_out
    k_gemm128<<<dim3(DM / 128, M / 128), 256, 0, stream>>>(Ob, WobT, out, DM, DM);
}